// Round 1
// baseline (50.324 us; speedup 1.0000x reference)
//
#include <hip/hip_runtime.h>

// TransformerBlockQuantum: B=32, S=4096, E=8, F=512, fp32 in/out.
// Per token: tv = x·Win^T; q = cos(tv+th_a); attn = q·Wout^T;
// h = LN1(x+attn); qf = cos(h)*cos(th_f);
// mid = qf·W1^T + b1; ffn = relu(mid)·W2^T + b2; out = LN2(h+ffn).
// One thread per token; weights in LDS (broadcast reads in f-loop).

constexpr int E = 8;
constexpr int F = 512;

__global__ __launch_bounds__(256) void qtb_kernel(
    const float* __restrict__ x,
    const float* __restrict__ Win,
    const float* __restrict__ th_attn,
    const float* __restrict__ Wout,
    const float* __restrict__ th_ffn,
    const float* __restrict__ W1,
    const float* __restrict__ b1,
    const float* __restrict__ W2,
    const float* __restrict__ b2,
    const float* __restrict__ g1, const float* __restrict__ bb1,
    const float* __restrict__ g2, const float* __restrict__ bb2,
    float* __restrict__ out, int ntok)
{
    // recs[f][0..1] = W1 row f (8 floats); recs[f][2..3] = W2^T row f (8 floats)
    __shared__ float4 recs[F][4];
    __shared__ float b1s[F];
    __shared__ float Win_s[64], Wout_s[64];
    __shared__ float tha_s[8], cthf_s[8], b2_s[8];
    __shared__ float g1_s[8], bb1_s[8], g2_s[8], bb2_s[8];

    const int tid = threadIdx.x;

    // ---- stage weights ----
    {
        const float4* W1v = reinterpret_cast<const float4*>(W1); // 1024 float4
        #pragma unroll
        for (int i = 0; i < 4; ++i) {
            int idx = tid + i * 256;      // 0..1023
            int f   = idx >> 1;
            int hlf = idx & 1;
            recs[f][hlf] = W1v[idx];
        }
        #pragma unroll
        for (int i = 0; i < 2; ++i) {
            int f = tid + i * 256;
            float w[8];
            #pragma unroll
            for (int e = 0; e < 8; ++e) w[e] = W2[e * F + f]; // coalesced per e
            recs[f][2] = make_float4(w[0], w[1], w[2], w[3]);
            recs[f][3] = make_float4(w[4], w[5], w[6], w[7]);
        }
        #pragma unroll
        for (int i = 0; i < 2; ++i) b1s[tid + i * 256] = b1[tid + i * 256];
        if (tid < 64) { Win_s[tid] = Win[tid]; Wout_s[tid] = Wout[tid]; }
        if (tid < 8) {
            tha_s[tid]  = th_attn[tid];
            cthf_s[tid] = __cosf(th_ffn[tid]);
            b2_s[tid]   = b2[tid];
            g1_s[tid]   = g1[tid];  bb1_s[tid] = bb1[tid];
            g2_s[tid]   = g2[tid];  bb2_s[tid] = bb2[tid];
        }
    }
    __syncthreads();

    const int tok = blockIdx.x * blockDim.x + threadIdx.x;
    if (tok >= ntok) return;

    // ---- load token (32 B coalesced) ----
    const float4* xv = reinterpret_cast<const float4*>(x + (size_t)tok * E);
    float4 x0 = xv[0], x1 = xv[1];
    float xr[8] = {x0.x, x0.y, x0.z, x0.w, x1.x, x1.y, x1.z, x1.w};

    // ---- quantum attention ----
    float q[8];
    #pragma unroll
    for (int f = 0; f < 8; ++f) {
        float tv = 0.f;
        #pragma unroll
        for (int e = 0; e < 8; ++e) tv += xr[e] * Win_s[f * 8 + e];
        q[f] = __cosf(tv + tha_s[f]);
    }
    float h[8];
    #pragma unroll
    for (int e = 0; e < 8; ++e) {
        float ao = 0.f;
        #pragma unroll
        for (int f = 0; f < 8; ++f) ao += q[f] * Wout_s[e * 8 + f];
        h[e] = xr[e] + ao;
    }

    // ---- LN1 ----
    {
        float m = 0.f;
        #pragma unroll
        for (int e = 0; e < 8; ++e) m += h[e];
        m *= 0.125f;
        float v = 0.f;
        #pragma unroll
        for (int e = 0; e < 8; ++e) { float d = h[e] - m; v += d * d; }
        v *= 0.125f;
        float rs = rsqrtf(v + 1e-5f);
        #pragma unroll
        for (int e = 0; e < 8; ++e) h[e] = (h[e] - m) * rs * g1_s[e] + bb1_s[e];
    }

    // ---- quantum FFN front ----
    float qf[8];
    #pragma unroll
    for (int e = 0; e < 8; ++e) qf[e] = __cosf(h[e]) * cthf_s[e];

    // ---- FFN main loop: 512 x (dot8 + relu + axpy8), LDS broadcast reads ----
    float acc[8] = {0, 0, 0, 0, 0, 0, 0, 0};
    #pragma unroll 4
    for (int f = 0; f < F; ++f) {
        float4 a = recs[f][0], b = recs[f][1];
        float mid = b1s[f];
        mid += qf[0] * a.x + qf[1] * a.y + qf[2] * a.z + qf[3] * a.w
             + qf[4] * b.x + qf[5] * b.y + qf[6] * b.z + qf[7] * b.w;
        float r = fmaxf(mid, 0.f);
        float4 c = recs[f][2], d4 = recs[f][3];
        acc[0] += r * c.x;  acc[1] += r * c.y;  acc[2] += r * c.z;  acc[3] += r * c.w;
        acc[4] += r * d4.x; acc[5] += r * d4.y; acc[6] += r * d4.z; acc[7] += r * d4.w;
    }

    // ---- LN2 + store ----
    float o[8];
    #pragma unroll
    for (int e = 0; e < 8; ++e) o[e] = h[e] + acc[e] + b2_s[e];
    float m2 = 0.f;
    #pragma unroll
    for (int e = 0; e < 8; ++e) m2 += o[e];
    m2 *= 0.125f;
    float v2 = 0.f;
    #pragma unroll
    for (int e = 0; e < 8; ++e) { float d = o[e] - m2; v2 += d * d; }
    v2 *= 0.125f;
    float rs2 = rsqrtf(v2 + 1e-5f);

    float4 o0, o1;
    o0.x = (o[0] - m2) * rs2 * g2_s[0] + bb2_s[0];
    o0.y = (o[1] - m2) * rs2 * g2_s[1] + bb2_s[1];
    o0.z = (o[2] - m2) * rs2 * g2_s[2] + bb2_s[2];
    o0.w = (o[3] - m2) * rs2 * g2_s[3] + bb2_s[3];
    o1.x = (o[4] - m2) * rs2 * g2_s[4] + bb2_s[4];
    o1.y = (o[5] - m2) * rs2 * g2_s[5] + bb2_s[5];
    o1.z = (o[6] - m2) * rs2 * g2_s[6] + bb2_s[6];
    o1.w = (o[7] - m2) * rs2 * g2_s[7] + bb2_s[7];
    float4* ov = reinterpret_cast<float4*>(out + (size_t)tok * E);
    ov[0] = o0; ov[1] = o1;
}

extern "C" void kernel_launch(void* const* d_in, const int* in_sizes, int n_in,
                              void* d_out, int out_size, void* d_ws, size_t ws_size,
                              hipStream_t stream) {
    const float* x       = (const float*)d_in[0];
    const float* Win     = (const float*)d_in[1];
    const float* th_attn = (const float*)d_in[2];
    const float* Wout    = (const float*)d_in[3];
    const float* th_ffn  = (const float*)d_in[4];
    const float* W1      = (const float*)d_in[5];
    const float* b1      = (const float*)d_in[6];
    const float* W2      = (const float*)d_in[7];
    const float* b2      = (const float*)d_in[8];
    const float* g1      = (const float*)d_in[9];
    const float* bb1     = (const float*)d_in[10];
    const float* g2      = (const float*)d_in[11];
    const float* bb2     = (const float*)d_in[12];
    float* out = (float*)d_out;

    const int ntok = in_sizes[0] / E;           // 131072
    const int blocks = (ntok + 255) / 256;      // 512
    qtb_kernel<<<blocks, 256, 0, stream>>>(x, Win, th_attn, Wout, th_ffn,
                                           W1, b1, W2, b2, g1, bb1, g2, bb2,
                                           out, ntok);
}

// Round 2
// 49.535 us; speedup vs baseline: 1.0159x; 1.0159x over previous
//
#include <hip/hip_runtime.h>

// TransformerBlockQuantum: B=32, S=4096, E=8, F=512, fp32 in/out.
// Per token: tv = x·Win^T; q = cos(tv+th_a); attn = q·Wout^T;
// h = LN1(x+attn); qf = cos(h)*cos(th_f);
// mid = qf·W1^T + b1; ffn = relu(mid)·W2^T + b2; out = LN2(h+ffn).
//
// Strategy: 4 waves per block, 64 tokens per block (1 token per lane).
// Each wave handles a wave-uniform quarter of the F=512 loop, so all
// weight indices are wave-uniform -> compiler emits scalar s_load
// (constant cache, scalar pipe, no LDS, no VALU address math).
// Cross-wave reduction of the 8 partial accumulators via 6KB LDS.
// Grid = 2048 blocks -> 8 blocks/CU -> 32 waves/CU (full occupancy).

constexpr int E = 8;
constexpr int F = 512;

__global__ void transpose_w2(const float* __restrict__ W2,
                             float* __restrict__ W2T) {
    int f = blockIdx.x * blockDim.x + threadIdx.x;
    if (f < F) {
        #pragma unroll
        for (int e = 0; e < E; ++e) W2T[f * E + e] = W2[e * F + f];
    }
}

__global__ __launch_bounds__(256, 8) void qtb_kernel(
    const float* __restrict__ x,
    const float* __restrict__ Win,
    const float* __restrict__ th_attn,
    const float* __restrict__ Wout,
    const float* __restrict__ th_ffn,
    const float* __restrict__ W1,
    const float* __restrict__ b1,
    const float* __restrict__ W2T,   // [F][E] transposed, in d_ws
    const float* __restrict__ b2,
    const float* __restrict__ g1, const float* __restrict__ bb1,
    const float* __restrict__ g2, const float* __restrict__ bb2,
    float* __restrict__ out, int ntok)
{
    __shared__ float part_acc[3][64][8];   // partial FFN sums from waves 1..3

    const int lane = threadIdx.x & 63;
    // wave-uniform part index, forced into an SGPR so weight loads are scalar
    const int part = __builtin_amdgcn_readfirstlane(threadIdx.x >> 6);
    const int tok  = blockIdx.x * 64 + lane;
    const bool valid = (tok < ntok);

    // ---- load token (32 B) ----
    float xr[8];
    if (valid) {
        const float4* xv = reinterpret_cast<const float4*>(x + (size_t)tok * E);
        float4 x0 = xv[0], x1 = xv[1];
        xr[0]=x0.x; xr[1]=x0.y; xr[2]=x0.z; xr[3]=x0.w;
        xr[4]=x1.x; xr[5]=x1.y; xr[6]=x1.z; xr[7]=x1.w;
    } else {
        #pragma unroll
        for (int e = 0; e < 8; ++e) xr[e] = 0.f;
    }

    // ---- quantum attention (uniform weight indices -> s_load) ----
    float q[8];
    #pragma unroll
    for (int f = 0; f < 8; ++f) {
        float tv = 0.f;
        #pragma unroll
        for (int e = 0; e < 8; ++e) tv += xr[e] * Win[f * 8 + e];
        q[f] = __cosf(tv + th_attn[f]);
    }
    float h[8];
    #pragma unroll
    for (int e = 0; e < 8; ++e) {
        float ao = 0.f;
        #pragma unroll
        for (int f = 0; f < 8; ++f) ao += q[f] * Wout[e * 8 + f];
        h[e] = xr[e] + ao;
    }

    // ---- LN1 ----
    {
        float m = 0.f;
        #pragma unroll
        for (int e = 0; e < 8; ++e) m += h[e];
        m *= 0.125f;
        float v = 0.f;
        #pragma unroll
        for (int e = 0; e < 8; ++e) { float d = h[e] - m; v += d * d; }
        v *= 0.125f;
        float rs = rsqrtf(v + 1e-5f);
        #pragma unroll
        for (int e = 0; e < 8; ++e) h[e] = (h[e] - m) * rs * g1[e] + bb1[e];
    }

    // ---- quantum FFN front ----
    float qf[8];
    #pragma unroll
    for (int e = 0; e < 8; ++e) qf[e] = __cosf(h[e]) * __cosf(th_ffn[e]);

    // ---- FFN: this wave's 128 f's; weights via scalar loads ----
    const float* __restrict__ W1r = W1  + (size_t)part * 128 * 8;
    const float* __restrict__ W2r = W2T + (size_t)part * 128 * 8;
    const float* __restrict__ b1r = b1  + (size_t)part * 128;

    float acc[8] = {0,0,0,0,0,0,0,0};
    #pragma unroll 2
    for (int i = 0; i < 128; ++i) {
        float mid = b1r[i];
        #pragma unroll
        for (int e = 0; e < 8; ++e) mid += qf[e] * W1r[i * 8 + e];
        float r = fmaxf(mid, 0.f);
        #pragma unroll
        for (int e = 0; e < 8; ++e) acc[e] += r * W2r[i * 8 + e];
    }

    // ---- cross-wave reduction ----
    if (part != 0) {
        #pragma unroll
        for (int e = 0; e < 8; ++e) part_acc[part - 1][lane][e] = acc[e];
    }
    __syncthreads();

    if (part == 0 && valid) {
        #pragma unroll
        for (int e = 0; e < 8; ++e)
            acc[e] += part_acc[0][lane][e] + part_acc[1][lane][e]
                    + part_acc[2][lane][e];

        // ---- LN2 + store ----
        float o[8];
        #pragma unroll
        for (int e = 0; e < 8; ++e) o[e] = h[e] + acc[e] + b2[e];
        float m2 = 0.f;
        #pragma unroll
        for (int e = 0; e < 8; ++e) m2 += o[e];
        m2 *= 0.125f;
        float v2 = 0.f;
        #pragma unroll
        for (int e = 0; e < 8; ++e) { float d = o[e] - m2; v2 += d * d; }
        v2 *= 0.125f;
        float rs2 = rsqrtf(v2 + 1e-5f);

        float4 o0, o1;
        o0.x = (o[0]-m2)*rs2*g2[0]+bb2[0];
        o0.y = (o[1]-m2)*rs2*g2[1]+bb2[1];
        o0.z = (o[2]-m2)*rs2*g2[2]+bb2[2];
        o0.w = (o[3]-m2)*rs2*g2[3]+bb2[3];
        o1.x = (o[4]-m2)*rs2*g2[4]+bb2[4];
        o1.y = (o[5]-m2)*rs2*g2[5]+bb2[5];
        o1.z = (o[6]-m2)*rs2*g2[6]+bb2[6];
        o1.w = (o[7]-m2)*rs2*g2[7]+bb2[7];
        float4* ov = reinterpret_cast<float4*>(out + (size_t)tok * E);
        ov[0] = o0; ov[1] = o1;
    }
}

extern "C" void kernel_launch(void* const* d_in, const int* in_sizes, int n_in,
                              void* d_out, int out_size, void* d_ws, size_t ws_size,
                              hipStream_t stream) {
    const float* x       = (const float*)d_in[0];
    const float* Win     = (const float*)d_in[1];
    const float* th_attn = (const float*)d_in[2];
    const float* Wout    = (const float*)d_in[3];
    const float* th_ffn  = (const float*)d_in[4];
    const float* W1      = (const float*)d_in[5];
    const float* b1      = (const float*)d_in[6];
    const float* W2      = (const float*)d_in[7];
    const float* b2      = (const float*)d_in[8];
    const float* g1      = (const float*)d_in[9];
    const float* bb1     = (const float*)d_in[10];
    const float* g2      = (const float*)d_in[11];
    const float* bb2     = (const float*)d_in[12];
    float* out = (float*)d_out;
    float* W2T = (float*)d_ws;               // [F][E] = 16 KB

    const int ntok = in_sizes[0] / E;        // 131072
    transpose_w2<<<(F + 255) / 256, 256, 0, stream>>>(W2, W2T);

    const int blocks = (ntok + 63) / 64;     // 2048
    qtb_kernel<<<blocks, 256, 0, stream>>>(x, Win, th_attn, Wout, th_ffn,
                                           W1, b1, W2T, b2, g1, bb1, g2, bb2,
                                           out, ntok);
}

// Round 3
// 27.560 us; speedup vs baseline: 1.8260x; 1.7974x over previous
//
#include <hip/hip_runtime.h>

// TransformerBlockQuantum: B=32, S=4096, E=8, F=512, fp32 in/out.
// Phase 1 (per lane, fp32): tv = x·Win^T; q=cos(tv+th_a); attn=q·Wout^T;
//   h = LN1(x+attn); qf = cos(h)*cos(th_f) -> bf16 -> LDS.
// Phase 2 (MFMA bf16): midT[f,tok] = W1·qfT  (A=W1 rows, B=qf frag);
//   r = relu(mid+b1) -> bf16, C-frag -> A-frag via 8x ds_bpermute;
//   out[tok,e] += r·W2^T  (B = W2[e][f] contiguous rows).
// Epilogue (per lane): residual + LN2 + store.
// Weights pre-converted to bf16 in d_ws by prep_weights.

typedef __attribute__((ext_vector_type(8))) short short8;
typedef __attribute__((ext_vector_type(4))) float f32x4;
typedef __attribute__((ext_vector_type(4))) int int4v;

constexpr int E = 8;
constexpr int F = 512;

static __device__ __forceinline__ unsigned short f2bf(float f) {
    unsigned u = __builtin_bit_cast(unsigned, f);
    u += 0x7FFFu + ((u >> 16) & 1u);            // RNE
    return (unsigned short)(u >> 16);
}

static __device__ __forceinline__ int cvt_pk_bf16(float lo, float hi) {
    int r;
    asm("v_cvt_pk_bf16_f32 %0, %1, %2" : "=v"(r) : "v"(lo), "v"(hi));
    return r;
}

__global__ void prep_weights(const float* __restrict__ W1,
                             const float* __restrict__ W2,
                             unsigned short* __restrict__ W1bf,
                             unsigned short* __restrict__ W2bf) {
    int i = blockIdx.x * blockDim.x + threadIdx.x;
    if (i < F * E) {
        W1bf[i] = f2bf(W1[i]);
        W2bf[i] = f2bf(W2[i]);
    }
}

__global__ __launch_bounds__(256, 4) void qtb_kernel(
    const float* __restrict__ x,
    const float* __restrict__ Win,
    const float* __restrict__ th_attn,
    const float* __restrict__ Wout,
    const float* __restrict__ th_ffn,
    const unsigned short* __restrict__ W1bf,
    const float* __restrict__ b1,
    const unsigned short* __restrict__ W2bf,
    const float* __restrict__ b2,
    const float* __restrict__ g1, const float* __restrict__ bb1,
    const float* __restrict__ g2, const float* __restrict__ bb2,
    float* __restrict__ out, int ntok)
{
    __shared__ short qf_lds[128 * 8];    // bf16 qf per token
    __shared__ float b1_lds[F];
    __shared__ float out_lds[128 * 8];   // fp32 FFN output per token

    const int tid  = threadIdx.x;
    const int lane = tid & 63;
    const int wv   = tid >> 6;

    // stage b1 (512 floats = 256 x float2, coalesced)
    reinterpret_cast<float2*>(b1_lds)[tid] =
        reinterpret_cast<const float2*>(b1)[tid];

    float h[8];
    if (tid < 128) {
        const int tok = blockIdx.x * 128 + tid;
        float xr[8];
        if (tok < ntok) {
            const float4* xv = reinterpret_cast<const float4*>(x + (size_t)tok * E);
            float4 x0 = xv[0], x1 = xv[1];
            xr[0]=x0.x; xr[1]=x0.y; xr[2]=x0.z; xr[3]=x0.w;
            xr[4]=x1.x; xr[5]=x1.y; xr[6]=x1.z; xr[7]=x1.w;
        } else {
            #pragma unroll
            for (int e = 0; e < 8; ++e) xr[e] = 0.f;
        }

        // quantum attention (uniform weight indices -> s_load)
        float q[8];
        #pragma unroll
        for (int f = 0; f < 8; ++f) {
            float tv = 0.f;
            #pragma unroll
            for (int e = 0; e < 8; ++e) tv += xr[e] * Win[f * 8 + e];
            q[f] = __cosf(tv + th_attn[f]);
        }
        #pragma unroll
        for (int e = 0; e < 8; ++e) {
            float ao = 0.f;
            #pragma unroll
            for (int f = 0; f < 8; ++f) ao += q[f] * Wout[e * 8 + f];
            h[e] = xr[e] + ao;
        }
        // LN1
        {
            float m = 0.f;
            #pragma unroll
            for (int e = 0; e < 8; ++e) m += h[e];
            m *= 0.125f;
            float v = 0.f;
            #pragma unroll
            for (int e = 0; e < 8; ++e) { float d = h[e] - m; v += d * d; }
            v *= 0.125f;
            float rs = rsqrtf(v + 1e-5f);
            #pragma unroll
            for (int e = 0; e < 8; ++e) h[e] = (h[e] - m) * rs * g1[e] + bb1[e];
        }
        // qf -> bf16 -> LDS
        float qf[8];
        #pragma unroll
        for (int e = 0; e < 8; ++e) qf[e] = __cosf(h[e]) * __cosf(th_ffn[e]);
        int4v qi = { cvt_pk_bf16(qf[0], qf[1]), cvt_pk_bf16(qf[2], qf[3]),
                     cvt_pk_bf16(qf[4], qf[5]), cvt_pk_bf16(qf[6], qf[7]) };
        *reinterpret_cast<int4v*>(&qf_lds[tid * 8]) = qi;
    }
    __syncthreads();

    // ---------------- MFMA phase: wave wv owns tokens [wv*32, wv*32+32) ----
    {
        const int tb   = wv * 32;
        const int lm   = lane & 15;
        const int lq   = lane >> 4;
        const bool lo16 = (lane < 16);
        const bool hi32 = (lane >= 32);
        const short8 zz = {};

        // B-operand qf frags (loop-invariant): lane<16 holds token tb+g*16+lm
        short8 bq[2];
        bq[0] = *reinterpret_cast<const short8*>(&qf_lds[(tb + lm) * 8]);
        bq[1] = *reinterpret_cast<const short8*>(&qf_lds[(tb + 16 + lm) * 8]);
        if (!lo16) { bq[0] = zz; bq[1] = zz; }

        // bpermute source-lane addresses (bytes): s = lm + 32*(lq&1) (+16)
        const int adA = 4 * (lm + 32 * (lq & 1));
        const int adB = adA + 64;

        f32x4 acc[2] = {{0.f,0.f,0.f,0.f},{0.f,0.f,0.f,0.f}};
        const f32x4* b1v = reinterpret_cast<const f32x4*>(b1_lds);

        #pragma unroll 2
        for (int c = 0; c < 16; ++c) {           // K2 chunk = 32 f's
            // A-operand for GEMM1: W1 rows (lane<16: row 32c+lm / +16)
            short8 aw0 = *reinterpret_cast<const short8*>(&W1bf[(32*c + lm) * 8]);
            short8 aw1 = *reinterpret_cast<const short8*>(&W1bf[(32*c + 16 + lm) * 8]);
            if (!lo16) { aw0 = zz; aw1 = zz; }
            // B-operand for GEMM2: lane holds W2[e=lm][32c + lq*8 .. +7]
            short8 wb2 = *reinterpret_cast<const short8*>(&W2bf[(lm & 7) * F + c*32 + lq*8]);
            if (lm >= 8) wb2 = zz;
            f32x4 bias0 = b1v[8*c + lq];         // b1[32c + 4lq .. +3]
            f32x4 bias1 = b1v[8*c + 4 + lq];     // b1[32c+16+4lq .. +3]

            #pragma unroll
            for (int g = 0; g < 2; ++g) {
                f32x4 zf = {0.f, 0.f, 0.f, 0.f};
                // midT tiles: lane holds f = 16t + 4lq + i, tok = tb+g*16+lm
                f32x4 d0 = __builtin_amdgcn_mfma_f32_16x16x32_bf16(aw0, bq[g], zf, 0, 0, 0);
                f32x4 d1 = __builtin_amdgcn_mfma_f32_16x16x32_bf16(aw1, bq[g], zf, 0, 0, 0);
                float r0[4], r1[4];
                #pragma unroll
                for (int i = 0; i < 4; ++i) {
                    r0[i] = fmaxf(d0[i] + bias0[i], 0.f);
                    r1[i] = fmaxf(d1[i] + bias1[i], 0.f);
                }
                int t0w0 = cvt_pk_bf16(r0[0], r0[1]);
                int t0w1 = cvt_pk_bf16(r0[2], r0[3]);
                int t1w0 = cvt_pk_bf16(r1[0], r1[1]);
                int t1w1 = cvt_pk_bf16(r1[2], r1[3]);
                // C-frag -> A-frag: lane lq needs f = 8lq..8lq+7 of its token
                int pA0 = __builtin_amdgcn_ds_bpermute(adA, t0w0);
                int pA1 = __builtin_amdgcn_ds_bpermute(adA, t0w1);
                int pB0 = __builtin_amdgcn_ds_bpermute(adB, t0w0);
                int pB1 = __builtin_amdgcn_ds_bpermute(adB, t0w1);
                int qA0 = __builtin_amdgcn_ds_bpermute(adA, t1w0);
                int qA1 = __builtin_amdgcn_ds_bpermute(adA, t1w1);
                int qB0 = __builtin_amdgcn_ds_bpermute(adB, t1w0);
                int qB1 = __builtin_amdgcn_ds_bpermute(adB, t1w1);
                int4v ai = { hi32 ? qA0 : pA0,
                             hi32 ? qA1 : pA1,
                             hi32 ? qB0 : pB0,
                             hi32 ? qB1 : pB1 };
                short8 a2 = __builtin_bit_cast(short8, ai);
                acc[g] = __builtin_amdgcn_mfma_f32_16x16x32_bf16(a2, wb2, acc[g], 0, 0, 0);
            }
        }

        // scatter FFN outputs: lane holds tok = tb+g*16+4lq+i, e = lm (<8)
        if (lm < 8) {
            #pragma unroll
            for (int g = 0; g < 2; ++g) {
                const int rowb = tb + g * 16 + lq * 4;
                #pragma unroll
                for (int i = 0; i < 4; ++i)
                    out_lds[(rowb + i) * 8 + lm] = acc[g][i];
            }
        }
    }
    __syncthreads();

    // ---------------- epilogue: residual + LN2 + store --------------------
    if (tid < 128) {
        const int tok = blockIdx.x * 128 + tid;
        if (tok < ntok) {
            const f32x4* fv = reinterpret_cast<const f32x4*>(&out_lds[tid * 8]);
            f32x4 f0 = fv[0], f1 = fv[1];
            float o[8];
            #pragma unroll
            for (int e = 0; e < 4; ++e) o[e] = h[e] + f0[e] + b2[e];
            #pragma unroll
            for (int e = 0; e < 4; ++e) o[e + 4] = h[e + 4] + f1[e] + b2[e + 4];
            float m2 = 0.f;
            #pragma unroll
            for (int e = 0; e < 8; ++e) m2 += o[e];
            m2 *= 0.125f;
            float v2 = 0.f;
            #pragma unroll
            for (int e = 0; e < 8; ++e) { float d = o[e] - m2; v2 += d * d; }
            v2 *= 0.125f;
            float rs2 = rsqrtf(v2 + 1e-5f);
            float4 o0, o1;
            o0.x = (o[0]-m2)*rs2*g2[0]+bb2[0];
            o0.y = (o[1]-m2)*rs2*g2[1]+bb2[1];
            o0.z = (o[2]-m2)*rs2*g2[2]+bb2[2];
            o0.w = (o[3]-m2)*rs2*g2[3]+bb2[3];
            o1.x = (o[4]-m2)*rs2*g2[4]+bb2[4];
            o1.y = (o[5]-m2)*rs2*g2[5]+bb2[5];
            o1.z = (o[6]-m2)*rs2*g2[6]+bb2[6];
            o1.w = (o[7]-m2)*rs2*g2[7]+bb2[7];
            float4* ov = reinterpret_cast<float4*>(out + (size_t)tok * E);
            ov[0] = o0; ov[1] = o1;
        }
    }
}

extern "C" void kernel_launch(void* const* d_in, const int* in_sizes, int n_in,
                              void* d_out, int out_size, void* d_ws, size_t ws_size,
                              hipStream_t stream) {
    const float* x       = (const float*)d_in[0];
    const float* Win     = (const float*)d_in[1];
    const float* th_attn = (const float*)d_in[2];
    const float* Wout    = (const float*)d_in[3];
    const float* th_ffn  = (const float*)d_in[4];
    const float* W1      = (const float*)d_in[5];
    const float* b1      = (const float*)d_in[6];
    const float* W2      = (const float*)d_in[7];
    const float* b2      = (const float*)d_in[8];
    const float* g1      = (const float*)d_in[9];
    const float* bb1     = (const float*)d_in[10];
    const float* g2      = (const float*)d_in[11];
    const float* bb2     = (const float*)d_in[12];
    float* out = (float*)d_out;

    unsigned short* W1bf = (unsigned short*)d_ws;          // 8 KB
    unsigned short* W2bf = W1bf + (size_t)F * E;           // 8 KB

    prep_weights<<<(F * E + 255) / 256, 256, 0, stream>>>(W1, W2, W1bf, W2bf);

    const int ntok = in_sizes[0] / E;            // 131072
    const int blocks = (ntok + 127) / 128;       // 1024
    qtb_kernel<<<blocks, 256, 0, stream>>>(x, Win, th_attn, Wout, th_ffn,
                                           W1bf, b1, W2bf, b2, g1, bb1, g2, bb2,
                                           out, ntok);
}

// Round 4
// 23.503 us; speedup vs baseline: 2.1412x; 1.1726x over previous
//
#include <hip/hip_runtime.h>

// TransformerBlockQuantum: B=32, S=4096, E=8, F=512, fp32 in/out.
// Single kernel, 256 tokens/block, grid 512.
//  Stage:  W1 -> bf16 LDS [512][8]; W2 -> bf16 LDS [8][528] (padded);
//          b1 -> f32 LDS.
//  Phase1: per-thread fp32 attention (s_load weights) + LN1 + qf=cos*cos
//          -> bf16 -> LDS (all 256 threads, 1 token each).
//  Phase2: per wave, 64 tokens (4 groups of 16):
//          midT = W1·qfT via mfma_16x16x32_bf16 with C = b1 frag (bias free);
//          relu -> bf16 (cvt_pk) -> C-frag->A-frag via 8 ds_bpermute;
//          out += r·W2^T via mfma (B = W2 rows from LDS).
//          All fragment loads exec-masked to active lanes (16/32).
//  Epilogue: residual + LN2 + store (all 256 threads).
// qf-buffer (4KB) and FFN-out buffer (8KB) share one LDS region.

typedef __attribute__((ext_vector_type(8))) short short8;
typedef __attribute__((ext_vector_type(4))) float f32x4;
typedef __attribute__((ext_vector_type(4))) int int4v;

constexpr int E = 8;
constexpr int F = 512;
constexpr int W2P = 528;            // padded W2 row stride (shorts), 16B-aligned

static __device__ __forceinline__ int cvt_pk_bf16(float lo, float hi) {
    int r;
    asm("v_cvt_pk_bf16_f32 %0, %1, %2" : "=v"(r) : "v"(lo), "v"(hi));
    return r;
}

__global__ __launch_bounds__(256, 2) void qtb_kernel(
    const float* __restrict__ x,
    const float* __restrict__ Win,
    const float* __restrict__ th_attn,
    const float* __restrict__ Wout,
    const float* __restrict__ th_ffn,
    const float* __restrict__ W1,
    const float* __restrict__ b1,
    const float* __restrict__ W2,
    const float* __restrict__ b2,
    const float* __restrict__ g1, const float* __restrict__ bb1,
    const float* __restrict__ g2, const float* __restrict__ bb2,
    float* __restrict__ out, int ntok)
{
    __shared__ __align__(16) short w1_lds[F * 8];       // 8 KB
    __shared__ __align__(16) short w2_lds[8 * W2P];     // 8.25 KB
    __shared__ __align__(16) float b1_lds[F];           // 2 KB
    __shared__ __align__(16) float scratch[256 * 8];    // 8 KB: qf(bf16) then out(f32)

    const int tid  = threadIdx.x;
    const int lane = tid & 63;
    const int wv   = tid >> 6;

    // ---------------- stage weights into LDS (bf16) ----------------------
    {
        // W1: thread t converts rows 2t, 2t+1 (16 floats, contiguous)
        const f32x4* W1v = reinterpret_cast<const f32x4*>(W1);
        f32x4 a = W1v[4 * tid + 0], b = W1v[4 * tid + 1];
        f32x4 c = W1v[4 * tid + 2], d = W1v[4 * tid + 3];
        int4v r0 = { cvt_pk_bf16(a[0], a[1]), cvt_pk_bf16(a[2], a[3]),
                     cvt_pk_bf16(b[0], b[1]), cvt_pk_bf16(b[2], b[3]) };
        int4v r1 = { cvt_pk_bf16(c[0], c[1]), cvt_pk_bf16(c[2], c[3]),
                     cvt_pk_bf16(d[0], d[1]), cvt_pk_bf16(d[2], d[3]) };
        reinterpret_cast<int4v*>(w1_lds)[2 * tid]     = r0;
        reinterpret_cast<int4v*>(w1_lds)[2 * tid + 1] = r1;

        // W2: thread t converts e = t>>5, 16-elem segment seg = t&31
        const int e = tid >> 5, seg = tid & 31;
        const f32x4* W2v = reinterpret_cast<const f32x4*>(W2 + e * F + seg * 16);
        f32x4 p = W2v[0], q = W2v[1], r = W2v[2], s = W2v[3];
        int4v s0 = { cvt_pk_bf16(p[0], p[1]), cvt_pk_bf16(p[2], p[3]),
                     cvt_pk_bf16(q[0], q[1]), cvt_pk_bf16(q[2], q[3]) };
        int4v s1 = { cvt_pk_bf16(r[0], r[1]), cvt_pk_bf16(r[2], r[3]),
                     cvt_pk_bf16(s[0], s[1]), cvt_pk_bf16(s[2], s[3]) };
        int4v* dst = reinterpret_cast<int4v*>(&w2_lds[e * W2P + seg * 16]);
        dst[0] = s0; dst[1] = s1;

        if (tid < 128)
            reinterpret_cast<f32x4*>(b1_lds)[tid] =
                reinterpret_cast<const f32x4*>(b1)[tid];
    }

    // ---------------- phase 1: per-token fp32 front -----------------------
    float h[8];
    {
        const int tok = blockIdx.x * 256 + tid;
        float xr[8];
        if (tok < ntok) {
            const f32x4* xv = reinterpret_cast<const f32x4*>(x + (size_t)tok * E);
            f32x4 x0 = xv[0], x1 = xv[1];
            #pragma unroll
            for (int e = 0; e < 4; ++e) { xr[e] = x0[e]; xr[e + 4] = x1[e]; }
        } else {
            #pragma unroll
            for (int e = 0; e < 8; ++e) xr[e] = 0.f;
        }

        float q[8];
        #pragma unroll
        for (int f = 0; f < 8; ++f) {
            float tv = 0.f;
            #pragma unroll
            for (int e = 0; e < 8; ++e) tv += xr[e] * Win[f * 8 + e];
            q[f] = __cosf(tv + th_attn[f]);
        }
        #pragma unroll
        for (int e = 0; e < 8; ++e) {
            float ao = 0.f;
            #pragma unroll
            for (int f = 0; f < 8; ++f) ao += q[f] * Wout[e * 8 + f];
            h[e] = xr[e] + ao;
        }
        float m = 0.f;
        #pragma unroll
        for (int e = 0; e < 8; ++e) m += h[e];
        m *= 0.125f;
        float v = 0.f;
        #pragma unroll
        for (int e = 0; e < 8; ++e) { float d = h[e] - m; v += d * d; }
        v *= 0.125f;
        float rs = rsqrtf(v + 1e-5f);
        #pragma unroll
        for (int e = 0; e < 8; ++e) h[e] = (h[e] - m) * rs * g1[e] + bb1[e];

        float qf[8];
        #pragma unroll
        for (int e = 0; e < 8; ++e) qf[e] = __cosf(h[e]) * __cosf(th_ffn[e]);
        int4v qi = { cvt_pk_bf16(qf[0], qf[1]), cvt_pk_bf16(qf[2], qf[3]),
                     cvt_pk_bf16(qf[4], qf[5]), cvt_pk_bf16(qf[6], qf[7]) };
        short* qfs = reinterpret_cast<short*>(scratch);
        *reinterpret_cast<int4v*>(&qfs[tid * 8]) = qi;
    }
    __syncthreads();

    // ---------------- phase 2: MFMA FFN, wave owns 64 tokens --------------
    {
        const int tb = wv * 64;
        const int lm = lane & 15;
        const int lq = lane >> 4;
        const bool lo16 = (lane < 16);
        const bool hi32 = (lane >= 32);
        const short8 zz = {};
        const short* qfs = reinterpret_cast<const short*>(scratch);

        short8 bq[4] = { zz, zz, zz, zz };
        if (lo16) {
            #pragma unroll
            for (int g = 0; g < 4; ++g)
                bq[g] = *reinterpret_cast<const short8*>(&qfs[(tb + g * 16 + lm) * 8]);
        }
        __syncthreads();   // all qf reads done before scratch is reused as out

        const int adA = 4 * (lm + 32 * (lq & 1));
        const int adB = adA + 64;
        const f32x4* b1v4 = reinterpret_cast<const f32x4*>(b1_lds);

        f32x4 acc[4] = {{0.f,0.f,0.f,0.f},{0.f,0.f,0.f,0.f},
                        {0.f,0.f,0.f,0.f},{0.f,0.f,0.f,0.f}};

        #pragma unroll 2
        for (int c = 0; c < 16; ++c) {
            short8 aw0 = zz, aw1 = zz;
            if (lo16) {
                aw0 = *reinterpret_cast<const short8*>(&w1_lds[(32 * c + lm) * 8]);
                aw1 = *reinterpret_cast<const short8*>(&w1_lds[(32 * c + 16 + lm) * 8]);
            }
            short8 wb2 = zz;
            if (lm < 8)
                wb2 = *reinterpret_cast<const short8*>(&w2_lds[lm * W2P + c * 32 + lq * 8]);
            f32x4 bias0 = b1v4[8 * c + lq];
            f32x4 bias1 = b1v4[8 * c + 4 + lq];

            #pragma unroll
            for (int g = 0; g < 4; ++g) {
                f32x4 d0 = __builtin_amdgcn_mfma_f32_16x16x32_bf16(aw0, bq[g], bias0, 0, 0, 0);
                f32x4 d1 = __builtin_amdgcn_mfma_f32_16x16x32_bf16(aw1, bq[g], bias1, 0, 0, 0);
                float r0[4], r1[4];
                #pragma unroll
                for (int i = 0; i < 4; ++i) {
                    r0[i] = fmaxf(d0[i], 0.f);
                    r1[i] = fmaxf(d1[i], 0.f);
                }
                int t0w0 = cvt_pk_bf16(r0[0], r0[1]);
                int t0w1 = cvt_pk_bf16(r0[2], r0[3]);
                int t1w0 = cvt_pk_bf16(r1[0], r1[1]);
                int t1w1 = cvt_pk_bf16(r1[2], r1[3]);
                int pA0 = __builtin_amdgcn_ds_bpermute(adA, t0w0);
                int pA1 = __builtin_amdgcn_ds_bpermute(adA, t0w1);
                int pB0 = __builtin_amdgcn_ds_bpermute(adB, t0w0);
                int pB1 = __builtin_amdgcn_ds_bpermute(adB, t0w1);
                int qA0 = __builtin_amdgcn_ds_bpermute(adA, t1w0);
                int qA1 = __builtin_amdgcn_ds_bpermute(adA, t1w1);
                int qB0 = __builtin_amdgcn_ds_bpermute(adB, t1w0);
                int qB1 = __builtin_amdgcn_ds_bpermute(adB, t1w1);
                int4v ai = { hi32 ? qA0 : pA0,
                             hi32 ? qA1 : pA1,
                             hi32 ? qB0 : pB0,
                             hi32 ? qB1 : pB1 };
                short8 a2 = __builtin_bit_cast(short8, ai);
                acc[g] = __builtin_amdgcn_mfma_f32_16x16x32_bf16(a2, wb2, acc[g], 0, 0, 0);
            }
        }

        // scatter FFN outputs: lane (e=lm<8) holds tokens tb+g*16+4lq+i
        float* outv = scratch;
        if (lm < 8) {
            #pragma unroll
            for (int g = 0; g < 4; ++g) {
                const int rowb = tb + g * 16 + lq * 4;
                #pragma unroll
                for (int i = 0; i < 4; ++i)
                    outv[(rowb + i) * 8 + lm] = acc[g][i];
            }
        }
    }
    __syncthreads();

    // ---------------- epilogue: residual + LN2 + store --------------------
    {
        const int tok = blockIdx.x * 256 + tid;
        if (tok < ntok) {
            const f32x4* fv = reinterpret_cast<const f32x4*>(&scratch[tid * 8]);
            f32x4 f0 = fv[0], f1 = fv[1];
            float o[8];
            #pragma unroll
            for (int e = 0; e < 4; ++e) o[e] = h[e] + f0[e] + b2[e];
            #pragma unroll
            for (int e = 0; e < 4; ++e) o[e + 4] = h[e + 4] + f1[e] + b2[e + 4];
            float m2 = 0.f;
            #pragma unroll
            for (int e = 0; e < 8; ++e) m2 += o[e];
            m2 *= 0.125f;
            float v2 = 0.f;
            #pragma unroll
            for (int e = 0; e < 8; ++e) { float d = o[e] - m2; v2 += d * d; }
            v2 *= 0.125f;
            float rs2 = rsqrtf(v2 + 1e-5f);
            f32x4 o0, o1;
            #pragma unroll
            for (int e = 0; e < 4; ++e) {
                o0[e] = (o[e]     - m2) * rs2 * g2[e]     + bb2[e];
                o1[e] = (o[e + 4] - m2) * rs2 * g2[e + 4] + bb2[e + 4];
            }
            f32x4* ov = reinterpret_cast<f32x4*>(out + (size_t)tok * E);
            ov[0] = o0; ov[1] = o1;
        }
    }
}

extern "C" void kernel_launch(void* const* d_in, const int* in_sizes, int n_in,
                              void* d_out, int out_size, void* d_ws, size_t ws_size,
                              hipStream_t stream) {
    const float* x       = (const float*)d_in[0];
    const float* Win     = (const float*)d_in[1];
    const float* th_attn = (const float*)d_in[2];
    const float* Wout    = (const float*)d_in[3];
    const float* th_ffn  = (const float*)d_in[4];
    const float* W1      = (const float*)d_in[5];
    const float* b1      = (const float*)d_in[6];
    const float* W2      = (const float*)d_in[7];
    const float* b2      = (const float*)d_in[8];
    const float* g1      = (const float*)d_in[9];
    const float* bb1     = (const float*)d_in[10];
    const float* g2      = (const float*)d_in[11];
    const float* bb2     = (const float*)d_in[12];
    float* out = (float*)d_out;

    const int ntok = in_sizes[0] / E;            // 131072
    const int blocks = (ntok + 255) / 256;       // 512
    qtb_kernel<<<blocks, 256, 0, stream>>>(x, Win, th_attn, Wout, th_ffn,
                                           W1, b1, W2, b2, g1, bb1, g2, bb2,
                                           out, ntok);
}

// Round 5
// 19.125 us; speedup vs baseline: 2.6312x; 1.2289x over previous
//
#include <hip/hip_runtime.h>

// TransformerBlockQuantum: B=32, S=4096, E=8, F=512, fp32 in/out.
// 128 tokens/block, 256 threads, grid 1024 (4 blocks/CU, 16 waves/CU).
//  Stage:  W1 -> bf16 LDS [512] short8; W2 -> bf16 LDS [8][66] short8 (padded);
//          b1 -> f32x4 LDS.
//  Phase1: tid<128: fp32 attention (s_load weights) + LN1 + qf=cos*cos
//          -> bf16 short8 -> LDS.
//  Phase2: wave wv owns 32 tokens (2 groups of 16):
//          midT = W1·qfT via mfma_16x16x32_bf16, C = b1 frag (bias free);
//          zero-padding lives only in bq's upper lanes -> aw/wb2 loads
//          are unmasked broadcasts;
//          relu -> cvt_pk -> 2x ds_write_b64 to per-(wave,group) mid tile,
//          2x ds_read_b64 back as GEMM2 A-frag (replaces 8 bpermutes);
//          out[tok,e] += r·W2^T via mfma (cols 8-15 garbage, never read).
//  Epilogue: residual + LN2 + store (tid<128).

typedef __attribute__((ext_vector_type(8))) short short8;
typedef __attribute__((ext_vector_type(4))) float f32x4;
typedef __attribute__((ext_vector_type(4))) int int4v;

constexpr int E = 8;
constexpr int F = 512;
constexpr int W2R  = 66;    // short8 per padded W2 row (528 shorts)
constexpr int TPB  = 128;   // tokens per block
constexpr int OSTR = 12;    // out_lds row stride in floats (48B, 16B-aligned)

static __device__ __forceinline__ int cvt_pk_bf16(float lo, float hi) {
    int r;
    asm("v_cvt_pk_bf16_f32 %0, %1, %2" : "=v"(r) : "v"(lo), "v"(hi));
    return r;
}

__global__ __launch_bounds__(256, 4) void qtb_kernel(
    const float* __restrict__ x,
    const float* __restrict__ Win,
    const float* __restrict__ th_attn,
    const float* __restrict__ Wout,
    const float* __restrict__ th_ffn,
    const float* __restrict__ W1,
    const float* __restrict__ b1,
    const float* __restrict__ W2,
    const float* __restrict__ b2,
    const float* __restrict__ g1, const float* __restrict__ bb1,
    const float* __restrict__ g2, const float* __restrict__ bb2,
    float* __restrict__ out, int ntok)
{
    __shared__ short8 w1_lds[F];                         // 8 KB
    __shared__ short8 w2_lds[8 * W2R];                   // 8.25 KB
    __shared__ f32x4  b1_lds[F / 4];                     // 2 KB
    __shared__ short8 qf_lds[TPB];                       // 2 KB
    __shared__ __align__(16) float out_lds[TPB * OSTR];  // 6 KB
    __shared__ int2   mid_lds[4][2][16][10];             // 10 KB

    const int tid  = threadIdx.x;
    const int lane = tid & 63;
    const int wv   = tid >> 6;

    // ---------------- stage weights into LDS (bf16) ----------------------
    {
        // W1: thread t converts rows 2t, 2t+1 (16 contiguous floats)
        const f32x4* W1v = reinterpret_cast<const f32x4*>(W1);
        f32x4 a = W1v[4 * tid + 0], b = W1v[4 * tid + 1];
        f32x4 c = W1v[4 * tid + 2], d = W1v[4 * tid + 3];
        int4v r0 = { cvt_pk_bf16(a[0], a[1]), cvt_pk_bf16(a[2], a[3]),
                     cvt_pk_bf16(b[0], b[1]), cvt_pk_bf16(b[2], b[3]) };
        int4v r1 = { cvt_pk_bf16(c[0], c[1]), cvt_pk_bf16(c[2], c[3]),
                     cvt_pk_bf16(d[0], d[1]), cvt_pk_bf16(d[2], d[3]) };
        w1_lds[2 * tid]     = __builtin_bit_cast(short8, r0);
        w1_lds[2 * tid + 1] = __builtin_bit_cast(short8, r1);

        // W2: thread t converts e = t>>5, 16-elem segment seg = t&31
        const int e = tid >> 5, seg = tid & 31;
        const f32x4* W2v = reinterpret_cast<const f32x4*>(W2 + e * F + seg * 16);
        f32x4 p = W2v[0], q = W2v[1], r = W2v[2], s = W2v[3];
        int4v s0 = { cvt_pk_bf16(p[0], p[1]), cvt_pk_bf16(p[2], p[3]),
                     cvt_pk_bf16(q[0], q[1]), cvt_pk_bf16(q[2], q[3]) };
        int4v s1 = { cvt_pk_bf16(r[0], r[1]), cvt_pk_bf16(r[2], r[3]),
                     cvt_pk_bf16(s[0], s[1]), cvt_pk_bf16(s[2], s[3]) };
        w2_lds[e * W2R + 2 * seg]     = __builtin_bit_cast(short8, s0);
        w2_lds[e * W2R + 2 * seg + 1] = __builtin_bit_cast(short8, s1);

        if (tid < 128)
            b1_lds[tid] = reinterpret_cast<const f32x4*>(b1)[tid];
    }

    // ---------------- phase 1: per-token fp32 front (tid<128) -------------
    float h[8];
    if (tid < TPB) {
        const int tok = blockIdx.x * TPB + tid;
        float xr[8];
        if (tok < ntok) {
            const f32x4* xv = reinterpret_cast<const f32x4*>(x + (size_t)tok * E);
            f32x4 x0 = xv[0], x1 = xv[1];
            #pragma unroll
            for (int e = 0; e < 4; ++e) { xr[e] = x0[e]; xr[e + 4] = x1[e]; }
        } else {
            #pragma unroll
            for (int e = 0; e < 8; ++e) xr[e] = 0.f;
        }

        float q[8];
        #pragma unroll
        for (int f = 0; f < 8; ++f) {
            float tv = 0.f;
            #pragma unroll
            for (int e = 0; e < 8; ++e) tv += xr[e] * Win[f * 8 + e];
            q[f] = __cosf(tv + th_attn[f]);
        }
        #pragma unroll
        for (int e = 0; e < 8; ++e) {
            float ao = 0.f;
            #pragma unroll
            for (int f = 0; f < 8; ++f) ao += q[f] * Wout[e * 8 + f];
            h[e] = xr[e] + ao;
        }
        float m = 0.f;
        #pragma unroll
        for (int e = 0; e < 8; ++e) m += h[e];
        m *= 0.125f;
        float v = 0.f;
        #pragma unroll
        for (int e = 0; e < 8; ++e) { float d = h[e] - m; v += d * d; }
        v *= 0.125f;
        float rs = rsqrtf(v + 1e-5f);
        #pragma unroll
        for (int e = 0; e < 8; ++e) h[e] = (h[e] - m) * rs * g1[e] + bb1[e];

        float qf[8];
        #pragma unroll
        for (int e = 0; e < 8; ++e) qf[e] = __cosf(h[e]) * __cosf(th_ffn[e]);
        int4v qi = { cvt_pk_bf16(qf[0], qf[1]), cvt_pk_bf16(qf[2], qf[3]),
                     cvt_pk_bf16(qf[4], qf[5]), cvt_pk_bf16(qf[6], qf[7]) };
        qf_lds[tid] = __builtin_bit_cast(short8, qi);
    }
    __syncthreads();

    // ---------------- phase 2: MFMA FFN, wave owns 32 tokens --------------
    {
        const int tb = wv * 32;
        const int lm = lane & 15;
        const int lq = lane >> 4;
        const short8 zz = {};

        // B-operand qf frags: broadcast load, zero K-pad lanes (lq>0)
        short8 bq[2];
        #pragma unroll
        for (int g = 0; g < 2; ++g) {
            bq[g] = qf_lds[tb + g * 16 + lm];
            if (lane >= 16) bq[g] = zz;
        }

        f32x4 acc[2] = {{0.f,0.f,0.f,0.f},{0.f,0.f,0.f,0.f}};
        const int e8 = lm & 7;

        #pragma unroll 2
        for (int c = 0; c < 16; ++c) {
            // A-op GEMM1: W1 rows, unmasked (K-pad handled by bq zeros)
            short8 aw0 = w1_lds[32 * c + lm];
            short8 aw1 = w1_lds[32 * c + 16 + lm];
            // B-op GEMM2: W2 row e8, k-slice; cols 8-15 garbage (never read)
            short8 wb2 = w2_lds[e8 * W2R + 4 * c + lq];
            f32x4 bias0 = b1_lds[8 * c + lq];
            f32x4 bias1 = b1_lds[8 * c + 4 + lq];

            #pragma unroll
            for (int g = 0; g < 2; ++g) {
                f32x4 d0 = __builtin_amdgcn_mfma_f32_16x16x32_bf16(aw0, bq[g], bias0, 0, 0, 0);
                f32x4 d1 = __builtin_amdgcn_mfma_f32_16x16x32_bf16(aw1, bq[g], bias1, 0, 0, 0);
                float r0[4], r1[4];
                #pragma unroll
                for (int i = 0; i < 4; ++i) {
                    r0[i] = fmaxf(d0[i], 0.f);
                    r1[i] = fmaxf(d1[i], 0.f);
                }
                int2 w0 = { cvt_pk_bf16(r0[0], r0[1]), cvt_pk_bf16(r0[2], r0[3]) };
                int2 w1 = { cvt_pk_bf16(r1[0], r1[1]), cvt_pk_bf16(r1[2], r1[3]) };
                // mid tile: element j of row lm holds f' = 4j..4j+3 (bf16)
                mid_lds[wv][g][lm][lq]     = w0;   // f' = 4lq..4lq+3
                mid_lds[wv][g][lm][4 + lq] = w1;   // f' = 16+4lq..+3
                // A-frag GEMM2: row tok=lm, k = f' 8lq..8lq+7
                int2 lo = mid_lds[wv][g][lm][2 * lq];
                int2 hi = mid_lds[wv][g][lm][2 * lq + 1];
                int4v ai = { lo.x, lo.y, hi.x, hi.y };
                short8 a2 = __builtin_bit_cast(short8, ai);
                acc[g] = __builtin_amdgcn_mfma_f32_16x16x32_bf16(a2, wb2, acc[g], 0, 0, 0);
            }
        }

        // scatter FFN outputs: lane (e=lm<8) holds tokens tb+g*16+4lq+i
        if (lm < 8) {
            #pragma unroll
            for (int g = 0; g < 2; ++g) {
                const int rowb = tb + g * 16 + lq * 4;
                #pragma unroll
                for (int i = 0; i < 4; ++i)
                    out_lds[(rowb + i) * OSTR + lm] = acc[g][i];
            }
        }
    }
    __syncthreads();

    // ---------------- epilogue: residual + LN2 + store --------------------
    if (tid < TPB) {
        const int tok = blockIdx.x * TPB + tid;
        if (tok < ntok) {
            const f32x4* fv = reinterpret_cast<const f32x4*>(&out_lds[tid * OSTR]);
            f32x4 f0 = fv[0], f1 = fv[1];
            float o[8];
            #pragma unroll
            for (int e = 0; e < 4; ++e) o[e] = h[e] + f0[e] + b2[e];
            #pragma unroll
            for (int e = 0; e < 4; ++e) o[e + 4] = h[e + 4] + f1[e] + b2[e + 4];
            float m2 = 0.f;
            #pragma unroll
            for (int e = 0; e < 8; ++e) m2 += o[e];
            m2 *= 0.125f;
            float v2 = 0.f;
            #pragma unroll
            for (int e = 0; e < 8; ++e) { float d = o[e] - m2; v2 += d * d; }
            v2 *= 0.125f;
            float rs2 = rsqrtf(v2 + 1e-5f);
            f32x4 o0, o1;
            #pragma unroll
            for (int e = 0; e < 4; ++e) {
                o0[e] = (o[e]     - m2) * rs2 * g2[e]     + bb2[e];
                o1[e] = (o[e + 4] - m2) * rs2 * g2[e + 4] + bb2[e + 4];
            }
            f32x4* ov = reinterpret_cast<f32x4*>(out + (size_t)tok * E);
            ov[0] = o0; ov[1] = o1;
        }
    }
}

extern "C" void kernel_launch(void* const* d_in, const int* in_sizes, int n_in,
                              void* d_out, int out_size, void* d_ws, size_t ws_size,
                              hipStream_t stream) {
    const float* x       = (const float*)d_in[0];
    const float* Win     = (const float*)d_in[1];
    const float* th_attn = (const float*)d_in[2];
    const float* Wout    = (const float*)d_in[3];
    const float* th_ffn  = (const float*)d_in[4];
    const float* W1      = (const float*)d_in[5];
    const float* b1      = (const float*)d_in[6];
    const float* W2      = (const float*)d_in[7];
    const float* b2      = (const float*)d_in[8];
    const float* g1      = (const float*)d_in[9];
    const float* bb1     = (const float*)d_in[10];
    const float* g2      = (const float*)d_in[11];
    const float* bb2     = (const float*)d_in[12];
    float* out = (float*)d_out;

    const int ntok = in_sizes[0] / E;            // 131072
    const int blocks = (ntok + TPB - 1) / TPB;   // 1024
    qtb_kernel<<<blocks, 256, 0, stream>>>(x, Win, th_attn, Wout, th_ffn,
                                           W1, b1, W2, b2, g1, bb1, g2, bb2,
                                           out, ntok);
}

// Round 6
// 16.817 us; speedup vs baseline: 2.9925x; 1.1373x over previous
//
#include <hip/hip_runtime.h>

// TransformerBlockQuantum: B=32, S=4096, E=8, F=512, fp32 in/out.
// 128 tokens/block, 256 threads, grid 1024 (4 blocks/CU, 16 waves/CU).
//  Stage:  W1 -> bf16 LDS [512] short8;
//          W2 -> bf16 LDS, K-PERMUTED so GEMM1's C-frag feeds GEMM2's A-frag
//                directly in-register (slot 8lq+i <-> f=32c+4lq+i / 32c+16+4lq+(i-4));
//          b1 -> f32x4 LDS.
//  Phase1: tid<128: fp32 attention (s_load weights) + LN1 + qf=cos*cos
//          -> bf16 short8 -> LDS.
//  Phase2: wave wv owns 32 tokens (2 groups of 16):
//          midT = W1·qfT via mfma_16x16x32_bf16, C = b1 frag (bias free);
//          relu -> cvt_pk -> A-frag IN REGISTER (no shuffle, no LDS bounce);
//          out[tok,e] += r·W2p via mfma. 5 DS reads + 6 MFMA per chunk.
//  Epilogue: residual + LN2 + store (tid<128).

typedef __attribute__((ext_vector_type(8))) short short8;
typedef __attribute__((ext_vector_type(4))) float f32x4;
typedef __attribute__((ext_vector_type(4))) int int4v;

constexpr int E = 8;
constexpr int F = 512;
constexpr int W2R  = 68;    // short8 stride per W2p row (64 + 4 pad)
constexpr int TPB  = 128;   // tokens per block
constexpr int OSTR = 12;    // out_lds row stride in floats (48B, 16B-aligned)

static __device__ __forceinline__ int cvt_pk_bf16(float lo, float hi) {
    int r;
    asm("v_cvt_pk_bf16_f32 %0, %1, %2" : "=v"(r) : "v"(lo), "v"(hi));
    return r;
}

__global__ __launch_bounds__(256, 4) void qtb_kernel(
    const float* __restrict__ x,
    const float* __restrict__ Win,
    const float* __restrict__ th_attn,
    const float* __restrict__ Wout,
    const float* __restrict__ th_ffn,
    const float* __restrict__ W1,
    const float* __restrict__ b1,
    const float* __restrict__ W2,
    const float* __restrict__ b2,
    const float* __restrict__ g1, const float* __restrict__ bb1,
    const float* __restrict__ g2, const float* __restrict__ bb2,
    float* __restrict__ out, int ntok)
{
    __shared__ short8 w1_lds[F];                         // 8 KB
    __shared__ short8 w2p_lds[8 * W2R];                  // 8.5 KB (K-permuted)
    __shared__ f32x4  b1_lds[F / 4];                     // 2 KB
    __shared__ short8 qf_lds[TPB];                       // 2 KB
    __shared__ __align__(16) float out_lds[TPB * OSTR];  // 6 KB

    const int tid  = threadIdx.x;
    const int lane = tid & 63;
    const int wv   = tid >> 6;

    // ---------------- stage weights into LDS (bf16) ----------------------
    {
        // W1: thread t converts rows 2t, 2t+1 (16 contiguous floats)
        const f32x4* W1v = reinterpret_cast<const f32x4*>(W1);
        f32x4 a = W1v[4 * tid + 0], b = W1v[4 * tid + 1];
        f32x4 c = W1v[4 * tid + 2], d = W1v[4 * tid + 3];
        int4v r0 = { cvt_pk_bf16(a[0], a[1]), cvt_pk_bf16(a[2], a[3]),
                     cvt_pk_bf16(b[0], b[1]), cvt_pk_bf16(b[2], b[3]) };
        int4v r1 = { cvt_pk_bf16(c[0], c[1]), cvt_pk_bf16(c[2], c[3]),
                     cvt_pk_bf16(d[0], d[1]), cvt_pk_bf16(d[2], d[3]) };
        w1_lds[2 * tid]     = __builtin_bit_cast(short8, r0);
        w1_lds[2 * tid + 1] = __builtin_bit_cast(short8, r1);

        // W2 K-permuted: slot record (e, c, lq) =
        //   bf16{ W2[e][32c+4lq..+3], W2[e][32c+16+4lq..+3] }
        #pragma unroll
        for (int rep = 0; rep < 2; ++rep) {
            const int idx = tid + rep * 256;       // 0..511
            const int e   = idx >> 6;
            const int c   = (idx & 63) >> 2;
            const int lq  = idx & 3;
            const f32x4* pa =
                reinterpret_cast<const f32x4*>(W2 + e * F + 32 * c + 4 * lq);
            f32x4 lo = pa[0];          // f = 32c+4lq .. +3
            f32x4 hi = pa[4];          // f = 32c+16+4lq .. +3
            int4v w = { cvt_pk_bf16(lo[0], lo[1]), cvt_pk_bf16(lo[2], lo[3]),
                        cvt_pk_bf16(hi[0], hi[1]), cvt_pk_bf16(hi[2], hi[3]) };
            w2p_lds[e * W2R + 4 * c + lq] = __builtin_bit_cast(short8, w);
        }

        if (tid < 128)
            b1_lds[tid] = reinterpret_cast<const f32x4*>(b1)[tid];
    }

    // ---------------- phase 1: per-token fp32 front (tid<128) -------------
    float h[8];
    if (tid < TPB) {
        const int tok = blockIdx.x * TPB + tid;
        float xr[8];
        if (tok < ntok) {
            const f32x4* xv = reinterpret_cast<const f32x4*>(x + (size_t)tok * E);
            f32x4 x0 = xv[0], x1 = xv[1];
            #pragma unroll
            for (int e = 0; e < 4; ++e) { xr[e] = x0[e]; xr[e + 4] = x1[e]; }
        } else {
            #pragma unroll
            for (int e = 0; e < 8; ++e) xr[e] = 0.f;
        }

        float q[8];
        #pragma unroll
        for (int f = 0; f < 8; ++f) {
            float tv = 0.f;
            #pragma unroll
            for (int e = 0; e < 8; ++e) tv += xr[e] * Win[f * 8 + e];
            q[f] = __cosf(tv + th_attn[f]);
        }
        #pragma unroll
        for (int e = 0; e < 8; ++e) {
            float ao = 0.f;
            #pragma unroll
            for (int f = 0; f < 8; ++f) ao += q[f] * Wout[e * 8 + f];
            h[e] = xr[e] + ao;
        }
        float m = 0.f;
        #pragma unroll
        for (int e = 0; e < 8; ++e) m += h[e];
        m *= 0.125f;
        float v = 0.f;
        #pragma unroll
        for (int e = 0; e < 8; ++e) { float d = h[e] - m; v += d * d; }
        v *= 0.125f;
        float rs = rsqrtf(v + 1e-5f);
        #pragma unroll
        for (int e = 0; e < 8; ++e) h[e] = (h[e] - m) * rs * g1[e] + bb1[e];

        float qf[8];
        #pragma unroll
        for (int e = 0; e < 8; ++e) qf[e] = __cosf(h[e]) * __cosf(th_ffn[e]);
        int4v qi = { cvt_pk_bf16(qf[0], qf[1]), cvt_pk_bf16(qf[2], qf[3]),
                     cvt_pk_bf16(qf[4], qf[5]), cvt_pk_bf16(qf[6], qf[7]) };
        qf_lds[tid] = __builtin_bit_cast(short8, qi);
    }
    __syncthreads();

    // ---------------- phase 2: MFMA FFN, wave owns 32 tokens --------------
    {
        const int tb = wv * 32;
        const int lm = lane & 15;
        const int lq = lane >> 4;
        const short8 zz = {};

        // B-operand qf frags: broadcast load, zero K-pad lanes (lq>0)
        short8 bq[2];
        #pragma unroll
        for (int g = 0; g < 2; ++g) {
            bq[g] = qf_lds[tb + g * 16 + lm];
            if (lane >= 16) bq[g] = zz;
        }

        f32x4 acc[2] = {{0.f,0.f,0.f,0.f},{0.f,0.f,0.f,0.f}};
        const int e8 = lm & 7;

        #pragma unroll 4
        for (int c = 0; c < 16; ++c) {
            // A-op GEMM1: W1 rows, unmasked (K-pad handled by bq zeros)
            short8 aw0 = w1_lds[32 * c + lm];
            short8 aw1 = w1_lds[32 * c + 16 + lm];
            // B-op GEMM2: K-permuted W2 record for (e8, c, lq)
            short8 wb2 = w2p_lds[e8 * W2R + 4 * c + lq];
            f32x4 bias0 = b1_lds[8 * c + lq];
            f32x4 bias1 = b1_lds[8 * c + 4 + lq];

            #pragma unroll
            for (int g = 0; g < 2; ++g) {
                f32x4 d0 = __builtin_amdgcn_mfma_f32_16x16x32_bf16(aw0, bq[g], bias0, 0, 0, 0);
                f32x4 d1 = __builtin_amdgcn_mfma_f32_16x16x32_bf16(aw1, bq[g], bias1, 0, 0, 0);
                float r0[4], r1[4];
                #pragma unroll
                for (int i = 0; i < 4; ++i) {
                    r0[i] = fmaxf(d0[i], 0.f);
                    r1[i] = fmaxf(d1[i], 0.f);
                }
                // A-frag for GEMM2 directly in-register: lane (lm,lq) holds
                // K-slots 8lq..8lq+7 = its own relu'd mid values.
                int4v ai = { cvt_pk_bf16(r0[0], r0[1]), cvt_pk_bf16(r0[2], r0[3]),
                             cvt_pk_bf16(r1[0], r1[1]), cvt_pk_bf16(r1[2], r1[3]) };
                short8 a2 = __builtin_bit_cast(short8, ai);
                acc[g] = __builtin_amdgcn_mfma_f32_16x16x32_bf16(a2, wb2, acc[g], 0, 0, 0);
            }
        }

        // scatter FFN outputs: lane (e=lm<8) holds tokens tb+g*16+4lq+i
        if (lm < 8) {
            #pragma unroll
            for (int g = 0; g < 2; ++g) {
                const int rowb = tb + g * 16 + lq * 4;
                #pragma unroll
                for (int i = 0; i < 4; ++i)
                    out_lds[(rowb + i) * OSTR + lm] = acc[g][i];
            }
        }
    }
    __syncthreads();

    // ---------------- epilogue: residual + LN2 + store --------------------
    if (tid < TPB) {
        const int tok = blockIdx.x * TPB + tid;
        if (tok < ntok) {
            const f32x4* fv = reinterpret_cast<const f32x4*>(&out_lds[tid * OSTR]);
            f32x4 f0 = fv[0], f1 = fv[1];
            float o[8];
            #pragma unroll
            for (int e = 0; e < 4; ++e) o[e] = h[e] + f0[e] + b2[e];
            #pragma unroll
            for (int e = 0; e < 4; ++e) o[e + 4] = h[e + 4] + f1[e] + b2[e + 4];
            float m2 = 0.f;
            #pragma unroll
            for (int e = 0; e < 8; ++e) m2 += o[e];
            m2 *= 0.125f;
            float v2 = 0.f;
            #pragma unroll
            for (int e = 0; e < 8; ++e) { float d = o[e] - m2; v2 += d * d; }
            v2 *= 0.125f;
            float rs2 = rsqrtf(v2 + 1e-5f);
            f32x4 o0, o1;
            #pragma unroll
            for (int e = 0; e < 4; ++e) {
                o0[e] = (o[e]     - m2) * rs2 * g2[e]     + bb2[e];
                o1[e] = (o[e + 4] - m2) * rs2 * g2[e + 4] + bb2[e + 4];
            }
            f32x4* ov = reinterpret_cast<f32x4*>(out + (size_t)tok * E);
            ov[0] = o0; ov[1] = o1;
        }
    }
}

extern "C" void kernel_launch(void* const* d_in, const int* in_sizes, int n_in,
                              void* d_out, int out_size, void* d_ws, size_t ws_size,
                              hipStream_t stream) {
    const float* x       = (const float*)d_in[0];
    const float* Win     = (const float*)d_in[1];
    const float* th_attn = (const float*)d_in[2];
    const float* Wout    = (const float*)d_in[3];
    const float* th_ffn  = (const float*)d_in[4];
    const float* W1      = (const float*)d_in[5];
    const float* b1      = (const float*)d_in[6];
    const float* W2      = (const float*)d_in[7];
    const float* b2      = (const float*)d_in[8];
    const float* g1      = (const float*)d_in[9];
    const float* bb1     = (const float*)d_in[10];
    const float* g2      = (const float*)d_in[11];
    const float* bb2     = (const float*)d_in[12];
    float* out = (float*)d_out;

    const int ntok = in_sizes[0] / E;            // 131072
    const int blocks = (ntok + TPB - 1) / TPB;   // 1024
    qtb_kernel<<<blocks, 256, 0, stream>>>(x, Win, th_attn, Wout, th_ffn,
                                           W1, b1, W2, b2, g1, bb1, g2, bb2,
                                           out, ntok);
}

// Round 7
// 15.531 us; speedup vs baseline: 3.2402x; 1.0828x over previous
//
#include <hip/hip_runtime.h>

// TransformerBlockQuantum: B=32, S=4096, E=8, F=512, fp32 in/out.
// Full-MFMA single kernel. 512 threads (8 waves), 256 tokens/block, grid 512.
// Each wave owns 32 tokens; lanes l and l+32 both serve token (l&31) (hi = l>>5
// selects the e-half / K-half). All inter-step "transposes" are absorbed into
// K-slot permutations of the staged weights, so after one staging barrier every
// wave is register-resident except 3 LDS b128 reads per FFN chunk.
//
//  attn:  D1 = Win·x^T (+theta via K-slots 8/9 vs const 1.0)  [1 mfma]
//         q = cos(D1 regs0-3);  D2 = Wout·q + C(=x residual)  [1 mfma]
//         4x shfl_xor(32) -> per-lane LN1 -> qf -> B-frag in-register.
//  FFN/chunk c (32 f):  mid = wab·qf (b1 via K8/9)            [1 mfma, 1 ds]
//         relu -> cvt_pk: regs0-7/8-15 ARE the two B-frags;
//         acc = W2p·relu (K-permuted recs)                    [2 mfma, 2 ds]
//  epilogue: +b2, shfl swap, LN2, coalesced f32x4 store.

typedef __attribute__((ext_vector_type(8)))  short short8;
typedef __attribute__((ext_vector_type(4)))  float f32x4;
typedef __attribute__((ext_vector_type(16))) float f32x16;
typedef __attribute__((ext_vector_type(4)))  int   int4v;

constexpr int E   = 8;
constexpr int F   = 512;
constexpr int TPB = 256;            // tokens per block

static __device__ __forceinline__ int cvt_pk_bf16(float lo, float hi) {
    int r;
    asm("v_cvt_pk_bf16_f32 %0, %1, %2" : "=v"(r) : "v"(lo), "v"(hi));
    return r;
}

// pack {bf16_hi(v), bf16(v - hi)} into one word (elem0 = hi part, elem1 = lo)
static __device__ __forceinline__ int hilo_bf16(float v) {
    unsigned u = __builtin_bit_cast(unsigned, v);
    float fh = __builtin_bit_cast(float, u & 0xFFFF0000u);
    return cvt_pk_bf16(fh, v - fh);
}

__global__ __launch_bounds__(512, 4) void qtb_kernel(
    const float* __restrict__ x,
    const float* __restrict__ Win,
    const float* __restrict__ th_attn,
    const float* __restrict__ Wout,
    const float* __restrict__ th_ffn,
    const float* __restrict__ W1,
    const float* __restrict__ b1,
    const float* __restrict__ W2,
    const float* __restrict__ b2,
    const float* __restrict__ g1, const float* __restrict__ bb1,
    const float* __restrict__ g2, const float* __restrict__ bb2,
    float* __restrict__ out, int ntok)
{
    __shared__ short8 wab[1024];    // [c][0-31: W1 row 32c+r | 32-63: b1 hi/lo rec]
    __shared__ short8 w2p[512];     // [c][m][hi][e8] K-permuted W2 recs
    __shared__ short8 attnA[64];    // Win rows / theta recs
    __shared__ short8 woutp[64];    // Wout K-permuted recs

    const int tid  = threadIdx.x;
    const int lane = tid & 63;
    const int wv   = tid >> 6;
    const int t32  = lane & 31;
    const int hi   = lane >> 5;
    const int e8   = t32 & 7;

    // ---------------- stage weights (once per block) ----------------------
    {
        // W1 row `tid` -> wab[64*(tid>>5) + (tid&31)]
        const f32x4* w1v = reinterpret_cast<const f32x4*>(W1 + tid * 8);
        f32x4 a = w1v[0], b = w1v[1];
        int4v rw1 = { cvt_pk_bf16(a[0], a[1]), cvt_pk_bf16(a[2], a[3]),
                      cvt_pk_bf16(b[0], b[1]), cvt_pk_bf16(b[2], b[3]) };
        wab[((tid >> 5) << 6) + (tid & 31)] = __builtin_bit_cast(short8, rw1);
        // b1 row `tid` -> wab[.. + 32 + ..]  (hi/lo split, K-slots 8/9)
        int4v rb1 = { hilo_bf16(b1[tid]), 0, 0, 0 };
        wab[((tid >> 5) << 6) + 32 + (tid & 31)] = __builtin_bit_cast(short8, rb1);
        // W2 K-permuted rec `tid`: e8=tid&7, h2=(tid>>3)&1, m=(tid>>4)&1, c=tid>>5
        const int se = tid & 7, sh = (tid >> 3) & 1, sm = (tid >> 4) & 1, sc = tid >> 5;
        const int f0 = sc * 32 + sm * 16 + sh * 4;
        const float* wp = W2 + se * F + f0;
        f32x4 p = *reinterpret_cast<const f32x4*>(wp);
        f32x4 q = *reinterpret_cast<const f32x4*>(wp + 8);
        int4v rw2 = { cvt_pk_bf16(p[0], p[1]), cvt_pk_bf16(p[2], p[3]),
                      cvt_pk_bf16(q[0], q[1]), cvt_pk_bf16(q[2], q[3]) };
        w2p[tid] = __builtin_bit_cast(short8, rw2);

        if (tid < 64) {           // attnA: lanes 0-31 Win rows, 32-63 theta recs
            const int tt = tid & 31;
            int4v ra = { 0, 0, 0, 0 };
            if (tt < 8) {
                if (tid < 32) {
                    const f32x4* wiv = reinterpret_cast<const f32x4*>(Win + tt * 8);
                    f32x4 wa = wiv[0], wb = wiv[1];
                    ra = int4v{ cvt_pk_bf16(wa[0], wa[1]), cvt_pk_bf16(wa[2], wa[3]),
                                cvt_pk_bf16(wb[0], wb[1]), cvt_pk_bf16(wb[2], wb[3]) };
                } else {
                    ra = int4v{ hilo_bf16(th_attn[tt]), 0, 0, 0 };
                }
            }
            attnA[tid] = __builtin_bit_cast(short8, ra);
        } else if (tid < 128) {   // woutp: rec (t32, hh) = {Wout[t32][4hh..+3], 0x4}
            const int l = tid - 64, tt = l & 31, hh = l >> 5;
            int4v ro = { 0, 0, 0, 0 };
            if (tt < 8) {
                const float* wo = Wout + tt * 8 + hh * 4;
                ro.x = cvt_pk_bf16(wo[0], wo[1]);
                ro.y = cvt_pk_bf16(wo[2], wo[3]);
            }
            woutp[l] = __builtin_bit_cast(short8, ro);
        }
    }
    __syncthreads();

    // ---------------- per-wave, fully independent --------------------------
    const int T = blockIdx.x * TPB + wv * 32 + t32;
    const bool valid = (T < ntok);
    const int ONE2 = 0x3F803F80;            // two bf16 1.0
    const f32x16 z16 = {};

    // token load (both hi-halves load the same 32 B; L1 broadcast)
    f32x4 x0 = {0.f,0.f,0.f,0.f}, x1 = {0.f,0.f,0.f,0.f};
    if (valid) {
        const f32x4* xv = reinterpret_cast<const f32x4*>(x + (size_t)T * E);
        x0 = xv[0]; x1 = xv[1];
    }

    // ---- attention GEMM1: D1 = Win·x^T + theta ----
    int4v bx = hi ? int4v{ ONE2, 0, 0, 0 }
                  : int4v{ cvt_pk_bf16(x0[0], x0[1]), cvt_pk_bf16(x0[2], x0[3]),
                           cvt_pk_bf16(x1[0], x1[1]), cvt_pk_bf16(x1[2], x1[3]) };
    short8 aA = attnA[lane];
    f32x16 d1 = __builtin_amdgcn_mfma_f32_32x32x16_bf16(
        aA, __builtin_bit_cast(short8, bx), z16, 0, 0, 0);

    // q = cos(tv + theta) for f = 4*hi + 0..3
    float qv0 = __cosf(d1[0]), qv1 = __cosf(d1[1]);
    float qv2 = __cosf(d1[2]), qv3 = __cosf(d1[3]);

    // ---- attention GEMM2: D2 = Wout·q + x (residual via C) ----
    int q01 = cvt_pk_bf16(qv0, qv1), q23 = cvt_pk_bf16(qv2, qv3);
    int4v bq2 = { q01, q23, q01, q23 };     // elems 4-7 junk, A has zeros there
    short8 aO = woutp[lane];
    f32x16 c2 = z16;
    c2[0] = hi ? x1[0] : x0[0];
    c2[1] = hi ? x1[1] : x0[1];
    c2[2] = hi ? x1[2] : x0[2];
    c2[3] = hi ? x1[3] : x0[3];
    f32x16 d2 = __builtin_amdgcn_mfma_f32_32x32x16_bf16(
        aO, __builtin_bit_cast(short8, bq2), c2, 0, 0, 0);

    // regs 0-3 = (x + attn)[e = 4hi + r]; swap halves to get all 8
    float po0 = d2[0], po1 = d2[1], po2 = d2[2], po3 = d2[3];
    float qo0 = __shfl_xor(po0, 32), qo1 = __shfl_xor(po1, 32);
    float qo2 = __shfl_xor(po2, 32), qo3 = __shfl_xor(po3, 32);
    float hv[8];
    hv[0] = hi ? qo0 : po0;  hv[1] = hi ? qo1 : po1;
    hv[2] = hi ? qo2 : po2;  hv[3] = hi ? qo3 : po3;
    hv[4] = hi ? po0 : qo0;  hv[5] = hi ? po1 : qo1;
    hv[6] = hi ? po2 : qo2;  hv[7] = hi ? po3 : qo3;

    // ---- LN1 (per lane, 2x redundant per token) ----
    float h[8];
    {
        float m = 0.f;
        #pragma unroll
        for (int e = 0; e < 8; ++e) m += hv[e];
        m *= 0.125f;
        float v = 0.f;
        #pragma unroll
        for (int e = 0; e < 8; ++e) { float d = hv[e] - m; v += d * d; }
        v *= 0.125f;
        float rs = rsqrtf(v + 1e-5f);
        #pragma unroll
        for (int e = 0; e < 8; ++e) h[e] = (hv[e] - m) * rs * g1[e] + bb1[e];
    }

    // ---- qf and FFN B-frag (in-register) ----
    float qf[8];
    #pragma unroll
    for (int e = 0; e < 8; ++e) qf[e] = __cosf(h[e]) * __cosf(th_ffn[e]);
    int4v bqf = hi ? int4v{ ONE2, 0, 0, 0 }
                   : int4v{ cvt_pk_bf16(qf[0], qf[1]), cvt_pk_bf16(qf[2], qf[3]),
                            cvt_pk_bf16(qf[4], qf[5]), cvt_pk_bf16(qf[6], qf[7]) };
    short8 bqfs = __builtin_bit_cast(short8, bqf);

    // ---- FFN main loop ----
    f32x16 acc = z16;
    #pragma unroll 4
    for (int c = 0; c < 16; ++c) {
        short8 aW = wab[(c << 6) + lane];
        f32x16 m1 = __builtin_amdgcn_mfma_f32_32x32x16_bf16(aW, bqfs, z16, 0, 0, 0);
        float r0  = fmaxf(m1[0], 0.f),  r1  = fmaxf(m1[1], 0.f);
        float r2  = fmaxf(m1[2], 0.f),  r3  = fmaxf(m1[3], 0.f);
        float r4  = fmaxf(m1[4], 0.f),  r5  = fmaxf(m1[5], 0.f);
        float r6  = fmaxf(m1[6], 0.f),  r7  = fmaxf(m1[7], 0.f);
        float r8  = fmaxf(m1[8], 0.f),  r9  = fmaxf(m1[9], 0.f);
        float r10 = fmaxf(m1[10], 0.f), r11 = fmaxf(m1[11], 0.f);
        float r12 = fmaxf(m1[12], 0.f), r13 = fmaxf(m1[13], 0.f);
        float r14 = fmaxf(m1[14], 0.f), r15 = fmaxf(m1[15], 0.f);
        int4v pA = { cvt_pk_bf16(r0,  r1),  cvt_pk_bf16(r2,  r3),
                     cvt_pk_bf16(r4,  r5),  cvt_pk_bf16(r6,  r7) };
        int4v pB = { cvt_pk_bf16(r8,  r9),  cvt_pk_bf16(r10, r11),
                     cvt_pk_bf16(r12, r13), cvt_pk_bf16(r14, r15) };
        short8 wa0 = w2p[(c << 5) + (hi << 3) + e8];
        short8 wa1 = w2p[(c << 5) + 16 + (hi << 3) + e8];
        acc = __builtin_amdgcn_mfma_f32_32x32x16_bf16(
            wa0, __builtin_bit_cast(short8, pA), acc, 0, 0, 0);
        acc = __builtin_amdgcn_mfma_f32_32x32x16_bf16(
            wa1, __builtin_bit_cast(short8, pB), acc, 0, 0, 0);
    }

    // ---- epilogue: +b2, swap halves, LN2, store ----
    float h0 = hi ? h[4] : h[0], h1 = hi ? h[5] : h[1];
    float h2 = hi ? h[6] : h[2], h3 = hi ? h[7] : h[3];
    float bz0 = hi ? b2[4] : b2[0], bz1 = hi ? b2[5] : b2[1];
    float bz2 = hi ? b2[6] : b2[2], bz3 = hi ? b2[7] : b2[3];
    float oh0 = h0 + acc[0] + bz0, oh1 = h1 + acc[1] + bz1;
    float oh2 = h2 + acc[2] + bz2, oh3 = h3 + acc[3] + bz3;
    float sw0 = __shfl_xor(oh0, 32), sw1 = __shfl_xor(oh1, 32);
    float sw2 = __shfl_xor(oh2, 32), sw3 = __shfl_xor(oh3, 32);
    float o[8];
    o[0] = hi ? sw0 : oh0;  o[1] = hi ? sw1 : oh1;
    o[2] = hi ? sw2 : oh2;  o[3] = hi ? sw3 : oh3;
    o[4] = hi ? oh0 : sw0;  o[5] = hi ? oh1 : sw1;
    o[6] = hi ? oh2 : sw2;  o[7] = hi ? oh3 : sw3;

    float m2 = 0.f;
    #pragma unroll
    for (int e = 0; e < 8; ++e) m2 += o[e];
    m2 *= 0.125f;
    float v2 = 0.f;
    #pragma unroll
    for (int e = 0; e < 8; ++e) { float d = o[e] - m2; v2 += d * d; }
    v2 *= 0.125f;
    float rs2 = rsqrtf(v2 + 1e-5f);
    float n[8];
    #pragma unroll
    for (int e = 0; e < 8; ++e) n[e] = (o[e] - m2) * rs2 * g2[e] + bb2[e];

    if (valid) {
        f32x4 st;
        st[0] = hi ? n[4] : n[0];  st[1] = hi ? n[5] : n[1];
        st[2] = hi ? n[6] : n[2];  st[3] = hi ? n[7] : n[3];
        *reinterpret_cast<f32x4*>(out + (size_t)T * E + hi * 4) = st;
    }
}

extern "C" void kernel_launch(void* const* d_in, const int* in_sizes, int n_in,
                              void* d_out, int out_size, void* d_ws, size_t ws_size,
                              hipStream_t stream) {
    const float* x       = (const float*)d_in[0];
    const float* Win     = (const float*)d_in[1];
    const float* th_attn = (const float*)d_in[2];
    const float* Wout    = (const float*)d_in[3];
    const float* th_ffn  = (const float*)d_in[4];
    const float* W1      = (const float*)d_in[5];
    const float* b1      = (const float*)d_in[6];
    const float* W2      = (const float*)d_in[7];
    const float* b2      = (const float*)d_in[8];
    const float* g1      = (const float*)d_in[9];
    const float* bb1     = (const float*)d_in[10];
    const float* g2      = (const float*)d_in[11];
    const float* bb2     = (const float*)d_in[12];
    float* out = (float*)d_out;
    (void)d_ws; (void)ws_size;

    const int ntok = in_sizes[0] / E;            // 131072
    const int blocks = (ntok + TPB - 1) / TPB;   // 512
    qtb_kernel<<<blocks, 512, 0, stream>>>(x, Win, th_attn, Wout, th_ffn,
                                           W1, b1, W2, b2, g1, bb1, g2, bb2,
                                           out, ntok);
}

// Round 9
// 15.430 us; speedup vs baseline: 3.2615x; 1.0066x over previous
//
#include <hip/hip_runtime.h>

// TransformerBlockQuantum: B=32, S=4096, E=8, F=512, fp32 in/out.
// Full-MFMA single kernel. 512 threads (8 waves), 256 tokens/block, grid 512.
// Each wave owns 32 tokens; lanes l and l+32 serve token (l&31), hi = l>>5
// selects the e-half / K-half. All inter-step transposes are absorbed into
// K-slot permutations of the staged weights.
//
//  attn:  D1 = Win·x^T (+theta via K-slots 8/9 vs const 1.0)  [1 mfma]
//         q = cos(D1 regs0-3);  D2 = Wout·q + C(=x residual)  [1 mfma]
//  LN1:   HALF-SPLIT: each lane reduces its native 4 elems (= its store half),
//         cross-half via 2x shfl_xor partial sums; E[x^2]-m^2 variance.
//  qf:    4 cos/lane * cth table (LDS) -> 2 packed words -> 1 shfl -> B-frag.
//  FFN/chunk c (32 f):  mid = wab·qf (b1 via K8/9)            [1 mfma, 1 ds]
//         relu = fmaxf(fp32) then cvt_pk (PROVEN path; v_pk_max_i16 trick
//         from round 8 is the suspected absmax-0.707 bug — do not reuse);
//         dual accumulators accA/accB (wa0/wa1) halve the MFMA dep chain.
//  epilogue: +b2, half-split LN2, coalesced f32x4 store.

typedef __attribute__((ext_vector_type(8)))  short short8;
typedef __attribute__((ext_vector_type(4)))  float f32x4;
typedef __attribute__((ext_vector_type(16))) float f32x16;
typedef __attribute__((ext_vector_type(4)))  int   int4v;

constexpr int E   = 8;
constexpr int F   = 512;
constexpr int TPB = 256;            // tokens per block

static __device__ __forceinline__ int cvt_pk_bf16(float lo, float hi) {
    int r;
    asm("v_cvt_pk_bf16_f32 %0, %1, %2" : "=v"(r) : "v"(lo), "v"(hi));
    return r;
}

// pack {bf16_hi(v), bf16(v - hi)} into one word (K-slot pair vs 1.0,1.0)
static __device__ __forceinline__ int hilo_bf16(float v) {
    unsigned u = __builtin_bit_cast(unsigned, v);
    float fh = __builtin_bit_cast(float, u & 0xFFFF0000u);
    return cvt_pk_bf16(fh, v - fh);
}

__global__ __launch_bounds__(512, 4) void qtb_kernel(
    const float* __restrict__ x,
    const float* __restrict__ Win,
    const float* __restrict__ th_attn,
    const float* __restrict__ Wout,
    const float* __restrict__ th_ffn,
    const float* __restrict__ W1,
    const float* __restrict__ b1,
    const float* __restrict__ W2,
    const float* __restrict__ b2,
    const float* __restrict__ g1, const float* __restrict__ bb1,
    const float* __restrict__ g2, const float* __restrict__ bb2,
    float* __restrict__ out, int ntok)
{
    __shared__ short8 wab[1024];    // [c][0-31: W1 row 32c+r | 32-63: b1 hi/lo rec]
    __shared__ short8 w2p[512];     // [c][m][hi][e8] K-permuted W2 recs
    __shared__ short8 attnA[64];    // Win rows / theta recs
    __shared__ short8 woutp[64];    // Wout K-permuted recs
    __shared__ __align__(16) float cth_lds[8];   // cos(th_ffn)

    const int tid  = threadIdx.x;
    const int lane = tid & 63;
    const int wv   = tid >> 6;
    const int t32  = lane & 31;
    const int hi   = lane >> 5;
    const int e8   = t32 & 7;

    // ---------------- stage weights (once per block) ----------------------
    {
        // W1 row `tid` -> wab[64*(tid>>5) + (tid&31)]
        const f32x4* w1v = reinterpret_cast<const f32x4*>(W1 + tid * 8);
        f32x4 a = w1v[0], b = w1v[1];
        int4v rw1 = { cvt_pk_bf16(a[0], a[1]), cvt_pk_bf16(a[2], a[3]),
                      cvt_pk_bf16(b[0], b[1]), cvt_pk_bf16(b[2], b[3]) };
        wab[((tid >> 5) << 6) + (tid & 31)] = __builtin_bit_cast(short8, rw1);
        // b1 row `tid` -> wab[.. + 32 + ..]  (hi/lo split, K-slots 8/9)
        int4v rb1 = { hilo_bf16(b1[tid]), 0, 0, 0 };
        wab[((tid >> 5) << 6) + 32 + (tid & 31)] = __builtin_bit_cast(short8, rb1);
        // W2 K-permuted rec `tid`
        const int se = tid & 7, sh = (tid >> 3) & 1, sm = (tid >> 4) & 1, sc = tid >> 5;
        const int f0 = sc * 32 + sm * 16 + sh * 4;
        const float* wp = W2 + se * F + f0;
        f32x4 p = *reinterpret_cast<const f32x4*>(wp);
        f32x4 q = *reinterpret_cast<const f32x4*>(wp + 8);
        int4v rw2 = { cvt_pk_bf16(p[0], p[1]), cvt_pk_bf16(p[2], p[3]),
                      cvt_pk_bf16(q[0], q[1]), cvt_pk_bf16(q[2], q[3]) };
        w2p[tid] = __builtin_bit_cast(short8, rw2);

        if (tid < 8) cth_lds[tid] = __cosf(th_ffn[tid]);

        if (tid < 64) {           // attnA: lanes 0-31 Win rows, 32-63 theta recs
            const int tt = tid & 31;
            int4v ra = { 0, 0, 0, 0 };
            if (tt < 8) {
                if (tid < 32) {
                    const f32x4* wiv = reinterpret_cast<const f32x4*>(Win + tt * 8);
                    f32x4 wa = wiv[0], wb = wiv[1];
                    ra = int4v{ cvt_pk_bf16(wa[0], wa[1]), cvt_pk_bf16(wa[2], wa[3]),
                                cvt_pk_bf16(wb[0], wb[1]), cvt_pk_bf16(wb[2], wb[3]) };
                } else {
                    ra = int4v{ hilo_bf16(th_attn[tt]), 0, 0, 0 };
                }
            }
            attnA[tid] = __builtin_bit_cast(short8, ra);
        } else if (tid < 128) {   // woutp: rec (t32, hh) = {Wout[t32][4hh..+3]}
            const int l = tid - 64, tt = l & 31, hh = l >> 5;
            int4v ro = { 0, 0, 0, 0 };
            if (tt < 8) {
                const float* wo = Wout + tt * 8 + hh * 4;
                ro.x = cvt_pk_bf16(wo[0], wo[1]);
                ro.y = cvt_pk_bf16(wo[2], wo[3]);
            }
            woutp[l] = __builtin_bit_cast(short8, ro);
        }
    }
    __syncthreads();

    // ---------------- per-wave, fully independent --------------------------
    const int T = blockIdx.x * TPB + wv * 32 + t32;
    const bool valid = (T < ntok);
    const int ONE2 = 0x3F803F80;            // two bf16 1.0
    const f32x16 z16 = {};

    f32x4 x0 = {0.f,0.f,0.f,0.f}, x1 = {0.f,0.f,0.f,0.f};
    if (valid) {
        const f32x4* xv = reinterpret_cast<const f32x4*>(x + (size_t)T * E);
        x0 = xv[0]; x1 = xv[1];
    }

    // ---- attention GEMM1: D1 = Win·x^T + theta ----
    int4v bx = hi ? int4v{ ONE2, 0, 0, 0 }
                  : int4v{ cvt_pk_bf16(x0[0], x0[1]), cvt_pk_bf16(x0[2], x0[3]),
                           cvt_pk_bf16(x1[0], x1[1]), cvt_pk_bf16(x1[2], x1[3]) };
    short8 aA = attnA[lane];
    f32x16 d1 = __builtin_amdgcn_mfma_f32_32x32x16_bf16(
        aA, __builtin_bit_cast(short8, bx), z16, 0, 0, 0);

    // q for f = 4*hi + 0..3 (native per half)
    float qv0 = __cosf(d1[0]), qv1 = __cosf(d1[1]);
    float qv2 = __cosf(d1[2]), qv3 = __cosf(d1[3]);

    // ---- attention GEMM2: D2 = Wout·q + x (residual via C) ----
    int q01 = cvt_pk_bf16(qv0, qv1), q23 = cvt_pk_bf16(qv2, qv3);
    int4v bq2 = { q01, q23, q01, q23 };     // elems 4-7 junk, A has zeros there
    short8 aO = woutp[lane];
    f32x16 c2 = z16;
    c2[0] = hi ? x1[0] : x0[0];
    c2[1] = hi ? x1[1] : x0[1];
    c2[2] = hi ? x1[2] : x0[2];
    c2[3] = hi ? x1[3] : x0[3];
    f32x16 d2 = __builtin_amdgcn_mfma_f32_32x32x16_bf16(
        aO, __builtin_bit_cast(short8, bq2), c2, 0, 0, 0);

    // ---- half-split LN1: lane reduces its native 4 elems (e = 4hi+i) ----
    float s0 = d2[0], s1 = d2[1], s2 = d2[2], s3 = d2[3];
    float ps = s0 + s1 + s2 + s3;
    float pq = s0*s0 + s1*s1 + s2*s2 + s3*s3;
    float mn = (ps + __shfl_xor(ps, 32)) * 0.125f;
    float vr = (pq + __shfl_xor(pq, 32)) * 0.125f - mn * mn;
    float rs = rsqrtf(vr + 1e-5f);
    float hn[4];
    hn[0] = (s0 - mn) * rs * g1[4 * hi + 0] + bb1[4 * hi + 0];
    hn[1] = (s1 - mn) * rs * g1[4 * hi + 1] + bb1[4 * hi + 1];
    hn[2] = (s2 - mn) * rs * g1[4 * hi + 2] + bb1[4 * hi + 2];
    hn[3] = (s3 - mn) * rs * g1[4 * hi + 3] + bb1[4 * hi + 3];

    // ---- qf (4 cos/lane, cth from LDS table) + B-frag via 2 shfl ----
    f32x4 cthv = *reinterpret_cast<const f32x4*>(&cth_lds[hi * 4]);
    float qf0 = __cosf(hn[0]) * cthv[0];
    float qf1 = __cosf(hn[1]) * cthv[1];
    float qf2 = __cosf(hn[2]) * cthv[2];
    float qf3 = __cosf(hn[3]) * cthv[3];
    int qa = cvt_pk_bf16(qf0, qf1), qb = cvt_pk_bf16(qf2, qf3);
    int oqa = __shfl_xor(qa, 32), oqb = __shfl_xor(qb, 32);
    int4v bqf = hi ? int4v{ ONE2, 0, 0, 0 }
                   : int4v{ qa, qb, oqa, oqb };
    short8 bqfs = __builtin_bit_cast(short8, bqf);

    // ---- FFN main loop: dual accumulators, fp32 fmax relu (proven) ----
    f32x16 accA = z16, accB = z16;
    #pragma unroll 4
    for (int c = 0; c < 16; ++c) {
        short8 aW = wab[(c << 6) + lane];
        f32x16 m1 = __builtin_amdgcn_mfma_f32_32x32x16_bf16(
            aW, bqfs, z16, 0, 0, 0);
        float r0  = fmaxf(m1[0], 0.f),  r1  = fmaxf(m1[1], 0.f);
        float r2  = fmaxf(m1[2], 0.f),  r3  = fmaxf(m1[3], 0.f);
        float r4  = fmaxf(m1[4], 0.f),  r5  = fmaxf(m1[5], 0.f);
        float r6  = fmaxf(m1[6], 0.f),  r7  = fmaxf(m1[7], 0.f);
        float r8  = fmaxf(m1[8], 0.f),  r9  = fmaxf(m1[9], 0.f);
        float r10 = fmaxf(m1[10], 0.f), r11 = fmaxf(m1[11], 0.f);
        float r12 = fmaxf(m1[12], 0.f), r13 = fmaxf(m1[13], 0.f);
        float r14 = fmaxf(m1[14], 0.f), r15 = fmaxf(m1[15], 0.f);
        int4v pA = { cvt_pk_bf16(r0,  r1),  cvt_pk_bf16(r2,  r3),
                     cvt_pk_bf16(r4,  r5),  cvt_pk_bf16(r6,  r7) };
        int4v pB = { cvt_pk_bf16(r8,  r9),  cvt_pk_bf16(r10, r11),
                     cvt_pk_bf16(r12, r13), cvt_pk_bf16(r14, r15) };
        short8 wa0 = w2p[(c << 5) + (hi << 3) + e8];
        short8 wa1 = w2p[(c << 5) + 16 + (hi << 3) + e8];
        accA = __builtin_amdgcn_mfma_f32_32x32x16_bf16(
            wa0, __builtin_bit_cast(short8, pA), accA, 0, 0, 0);
        accB = __builtin_amdgcn_mfma_f32_32x32x16_bf16(
            wa1, __builtin_bit_cast(short8, pB), accB, 0, 0, 0);
    }

    // ---- epilogue: +b2, half-split LN2, store ----
    float oi[4];
    #pragma unroll
    for (int i = 0; i < 4; ++i)
        oi[i] = hn[i] + accA[i] + accB[i] + b2[4 * hi + i];
    float ps2 = oi[0] + oi[1] + oi[2] + oi[3];
    float pq2 = oi[0]*oi[0] + oi[1]*oi[1] + oi[2]*oi[2] + oi[3]*oi[3];
    float m2 = (ps2 + __shfl_xor(ps2, 32)) * 0.125f;
    float v2 = (pq2 + __shfl_xor(pq2, 32)) * 0.125f - m2 * m2;
    float rs2 = rsqrtf(v2 + 1e-5f);

    if (valid) {
        f32x4 st;
        #pragma unroll
        for (int i = 0; i < 4; ++i)
            st[i] = (oi[i] - m2) * rs2 * g2[4 * hi + i] + bb2[4 * hi + i];
        *reinterpret_cast<f32x4*>(out + (size_t)T * E + hi * 4) = st;
    }
}

extern "C" void kernel_launch(void* const* d_in, const int* in_sizes, int n_in,
                              void* d_out, int out_size, void* d_ws, size_t ws_size,
                              hipStream_t stream) {
    const float* x       = (const float*)d_in[0];
    const float* Win     = (const float*)d_in[1];
    const float* th_attn = (const float*)d_in[2];
    const float* Wout    = (const float*)d_in[3];
    const float* th_ffn  = (const float*)d_in[4];
    const float* W1      = (const float*)d_in[5];
    const float* b1      = (const float*)d_in[6];
    const float* W2      = (const float*)d_in[7];
    const float* b2      = (const float*)d_in[8];
    const float* g1      = (const float*)d_in[9];
    const float* bb1     = (const float*)d_in[10];
    const float* g2      = (const float*)d_in[11];
    const float* bb2     = (const float*)d_in[12];
    float* out = (float*)d_out;
    (void)d_ws; (void)ws_size;

    const int ntok = in_sizes[0] / E;            // 131072
    const int blocks = (ntok + TPB - 1) / TPB;   // 512
    qtb_kernel<<<blocks, 512, 0, stream>>>(x, Win, th_attn, Wout, th_ffn,
                                           W1, b1, W2, b2, g1, bb1, g2, bb2,
                                           out, ntok);
}

// Round 11
// 15.194 us; speedup vs baseline: 3.3121x; 1.0155x over previous
//
#include <hip/hip_runtime.h>

// TransformerBlockQuantum: B=32, S=4096, E=8, F=512, fp32 in/out.
// Full-MFMA single kernel. 1024 threads (16 waves), 512 tokens/block, grid 256
// (1 block/CU, 16 waves/CU). Each wave owns 32 tokens; lanes l / l+32 serve
// token (l&31), hi = l>>5 picks the e-half / K-half. All inter-step transposes
// are absorbed into K-slot permutations of the LDS-staged weights.
// Staging is split: tid<512 build W1|b1 recs, tid>=512 build W2 recs
// (halves per-CU staging vs the 512-thread version).
//
//  attn:  D1 = Win·x^T (+theta via K-slots 8/9 vs const 1.0)  [1 mfma]
//         q = cos(D1 regs0-3);  D2 = Wout·q + C(=x residual)  [1 mfma]
//  LN1:   half-split: lane reduces its native 4 elems, cross-half via
//         2x shfl_xor partial sums; E[x^2]-m^2 variance.
//  qf:    4 cos/lane * cth table -> 2 packed words -> 2 shfl -> B-frag.
//  FFN/chunk c:  mid = wab·qf (b1 via K8/9)  [1 mfma, 1 ds];
//         relu = fmaxf + cvt_pk (v_pk_max_i16 trick = round-8 bug, banned;
//         global-wab-via-prep-kernel = round-10 bug, banned);
//         dual accumulators accA/accB halve the MFMA dep chain  [2 mfma, 2 ds].
//  epilogue: +b2, half-split LN2, coalesced f32x4 store.

typedef __attribute__((ext_vector_type(8)))  short short8;
typedef __attribute__((ext_vector_type(4)))  float f32x4;
typedef __attribute__((ext_vector_type(16))) float f32x16;
typedef __attribute__((ext_vector_type(4)))  int   int4v;

constexpr int E   = 8;
constexpr int F   = 512;
constexpr int TPB = 512;            // tokens per block

static __device__ __forceinline__ int cvt_pk_bf16(float lo, float hi) {
    int r;
    asm("v_cvt_pk_bf16_f32 %0, %1, %2" : "=v"(r) : "v"(lo), "v"(hi));
    return r;
}

// pack {bf16_hi(v), bf16(v - hi)} into one word (K-slot pair vs 1.0,1.0)
static __device__ __forceinline__ int hilo_bf16(float v) {
    unsigned u = __builtin_bit_cast(unsigned, v);
    float fh = __builtin_bit_cast(float, u & 0xFFFF0000u);
    return cvt_pk_bf16(fh, v - fh);
}

__global__ __launch_bounds__(1024, 4) void qtb_kernel(
    const float* __restrict__ x,
    const float* __restrict__ Win,
    const float* __restrict__ th_attn,
    const float* __restrict__ Wout,
    const float* __restrict__ th_ffn,
    const float* __restrict__ W1,
    const float* __restrict__ b1,
    const float* __restrict__ W2,
    const float* __restrict__ b2,
    const float* __restrict__ g1, const float* __restrict__ bb1,
    const float* __restrict__ g2, const float* __restrict__ bb2,
    float* __restrict__ out, int ntok)
{
    __shared__ short8 wab[1024];    // [c][0-31: W1 row 32c+r | 32-63: b1 hi/lo rec]
    __shared__ short8 w2p[512];     // [c][m][hi][e8] K-permuted W2 recs
    __shared__ short8 attnA[64];    // Win rows / theta recs
    __shared__ short8 woutp[64];    // Wout K-permuted recs
    __shared__ __align__(16) float cth_lds[8];   // cos(th_ffn)

    const int tid  = threadIdx.x;
    const int lane = tid & 63;
    const int wv   = tid >> 6;        // 0..15
    const int t32  = lane & 31;
    const int hi   = lane >> 5;
    const int e8   = t32 & 7;

    // ---------------- stage weights (split across thread halves) ----------
    if (tid < 512) {
        // W1 row `tid` -> wab[64*(tid>>5) + (tid&31)]
        const f32x4* w1v = reinterpret_cast<const f32x4*>(W1 + tid * 8);
        f32x4 a = w1v[0], b = w1v[1];
        int4v rw1 = { cvt_pk_bf16(a[0], a[1]), cvt_pk_bf16(a[2], a[3]),
                      cvt_pk_bf16(b[0], b[1]), cvt_pk_bf16(b[2], b[3]) };
        wab[((tid >> 5) << 6) + (tid & 31)] = __builtin_bit_cast(short8, rw1);
        // b1 row `tid` -> wab[.. + 32 + ..]  (hi/lo split, K-slots 8/9)
        int4v rb1 = { hilo_bf16(b1[tid]), 0, 0, 0 };
        wab[((tid >> 5) << 6) + 32 + (tid & 31)] = __builtin_bit_cast(short8, rb1);

        if (tid < 8) cth_lds[tid] = __cosf(th_ffn[tid]);

        if (tid < 64) {           // attnA: lanes 0-31 Win rows, 32-63 theta recs
            const int tt = tid & 31;
            int4v ra = { 0, 0, 0, 0 };
            if (tt < 8) {
                if (tid < 32) {
                    const f32x4* wiv = reinterpret_cast<const f32x4*>(Win + tt * 8);
                    f32x4 wa = wiv[0], wb = wiv[1];
                    ra = int4v{ cvt_pk_bf16(wa[0], wa[1]), cvt_pk_bf16(wa[2], wa[3]),
                                cvt_pk_bf16(wb[0], wb[1]), cvt_pk_bf16(wb[2], wb[3]) };
                } else {
                    ra = int4v{ hilo_bf16(th_attn[tt]), 0, 0, 0 };
                }
            }
            attnA[tid] = __builtin_bit_cast(short8, ra);
        } else if (tid < 128) {   // woutp: rec (t32, hh) = {Wout[t32][4hh..+3]}
            const int l = tid - 64, tt = l & 31, hh = l >> 5;
            int4v ro = { 0, 0, 0, 0 };
            if (tt < 8) {
                const float* wo = Wout + tt * 8 + hh * 4;
                ro.x = cvt_pk_bf16(wo[0], wo[1]);
                ro.y = cvt_pk_bf16(wo[2], wo[3]);
            }
            woutp[l] = __builtin_bit_cast(short8, ro);
        }
    } else {
        // W2 K-permuted rec r = tid-512
        const int r  = tid - 512;
        const int se = r & 7, sh = (r >> 3) & 1, sm = (r >> 4) & 1, sc = r >> 5;
        const int f0 = sc * 32 + sm * 16 + sh * 4;
        const float* wp = W2 + se * F + f0;
        f32x4 p = *reinterpret_cast<const f32x4*>(wp);
        f32x4 q = *reinterpret_cast<const f32x4*>(wp + 8);
        int4v rw2 = { cvt_pk_bf16(p[0], p[1]), cvt_pk_bf16(p[2], p[3]),
                      cvt_pk_bf16(q[0], q[1]), cvt_pk_bf16(q[2], q[3]) };
        w2p[r] = __builtin_bit_cast(short8, rw2);
    }
    __syncthreads();

    // ---------------- per-wave, fully independent --------------------------
    const int T = blockIdx.x * TPB + wv * 32 + t32;
    const bool valid = (T < ntok);
    const int ONE2 = 0x3F803F80;            // two bf16 1.0
    const f32x16 z16 = {};

    f32x4 x0 = {0.f,0.f,0.f,0.f}, x1 = {0.f,0.f,0.f,0.f};
    if (valid) {
        const f32x4* xv = reinterpret_cast<const f32x4*>(x + (size_t)T * E);
        x0 = xv[0]; x1 = xv[1];
    }

    // ---- attention GEMM1: D1 = Win·x^T + theta ----
    int4v bx = hi ? int4v{ ONE2, 0, 0, 0 }
                  : int4v{ cvt_pk_bf16(x0[0], x0[1]), cvt_pk_bf16(x0[2], x0[3]),
                           cvt_pk_bf16(x1[0], x1[1]), cvt_pk_bf16(x1[2], x1[3]) };
    short8 aA = attnA[lane];
    f32x16 d1 = __builtin_amdgcn_mfma_f32_32x32x16_bf16(
        aA, __builtin_bit_cast(short8, bx), z16, 0, 0, 0);

    // q for f = 4*hi + 0..3 (native per half)
    float qv0 = __cosf(d1[0]), qv1 = __cosf(d1[1]);
    float qv2 = __cosf(d1[2]), qv3 = __cosf(d1[3]);

    // ---- attention GEMM2: D2 = Wout·q + x (residual via C) ----
    int q01 = cvt_pk_bf16(qv0, qv1), q23 = cvt_pk_bf16(qv2, qv3);
    int4v bq2 = { q01, q23, q01, q23 };     // elems 4-7 junk, A has zeros there
    short8 aO = woutp[lane];
    f32x16 c2 = z16;
    c2[0] = hi ? x1[0] : x0[0];
    c2[1] = hi ? x1[1] : x0[1];
    c2[2] = hi ? x1[2] : x0[2];
    c2[3] = hi ? x1[3] : x0[3];
    f32x16 d2 = __builtin_amdgcn_mfma_f32_32x32x16_bf16(
        aO, __builtin_bit_cast(short8, bq2), c2, 0, 0, 0);

    // ---- half-split LN1: lane reduces its native 4 elems (e = 4hi+i) ----
    float s0 = d2[0], s1 = d2[1], s2 = d2[2], s3 = d2[3];
    float ps = s0 + s1 + s2 + s3;
    float pq = s0*s0 + s1*s1 + s2*s2 + s3*s3;
    float mn = (ps + __shfl_xor(ps, 32)) * 0.125f;
    float vr = (pq + __shfl_xor(pq, 32)) * 0.125f - mn * mn;
    float rs = rsqrtf(vr + 1e-5f);
    float hn[4];
    hn[0] = (s0 - mn) * rs * g1[4 * hi + 0] + bb1[4 * hi + 0];
    hn[1] = (s1 - mn) * rs * g1[4 * hi + 1] + bb1[4 * hi + 1];
    hn[2] = (s2 - mn) * rs * g1[4 * hi + 2] + bb1[4 * hi + 2];
    hn[3] = (s3 - mn) * rs * g1[4 * hi + 3] + bb1[4 * hi + 3];

    // ---- qf (4 cos/lane, cth table) + B-frag via 2 shfl ----
    f32x4 cthv = *reinterpret_cast<const f32x4*>(&cth_lds[hi * 4]);
    float qf0 = __cosf(hn[0]) * cthv[0];
    float qf1 = __cosf(hn[1]) * cthv[1];
    float qf2 = __cosf(hn[2]) * cthv[2];
    float qf3 = __cosf(hn[3]) * cthv[3];
    int qa = cvt_pk_bf16(qf0, qf1), qb = cvt_pk_bf16(qf2, qf3);
    int oqa = __shfl_xor(qa, 32), oqb = __shfl_xor(qb, 32);
    int4v bqf = hi ? int4v{ ONE2, 0, 0, 0 }
                   : int4v{ qa, qb, oqa, oqb };
    short8 bqfs = __builtin_bit_cast(short8, bqf);

    // ---- FFN main loop: dual accumulators, fp32 fmax relu (proven) ----
    f32x16 accA = z16, accB = z16;
    #pragma unroll 4
    for (int c = 0; c < 16; ++c) {
        short8 aW = wab[(c << 6) + lane];
        f32x16 m1 = __builtin_amdgcn_mfma_f32_32x32x16_bf16(
            aW, bqfs, z16, 0, 0, 0);
        float r0  = fmaxf(m1[0], 0.f),  r1  = fmaxf(m1[1], 0.f);
        float r2  = fmaxf(m1[2], 0.f),  r3  = fmaxf(m1[3], 0.f);
        float r4  = fmaxf(m1[4], 0.f),  r5  = fmaxf(m1[5], 0.f);
        float r6  = fmaxf(m1[6], 0.f),  r7  = fmaxf(m1[7], 0.f);
        float r8  = fmaxf(m1[8], 0.f),  r9  = fmaxf(m1[9], 0.f);
        float r10 = fmaxf(m1[10], 0.f), r11 = fmaxf(m1[11], 0.f);
        float r12 = fmaxf(m1[12], 0.f), r13 = fmaxf(m1[13], 0.f);
        float r14 = fmaxf(m1[14], 0.f), r15 = fmaxf(m1[15], 0.f);
        int4v pA = { cvt_pk_bf16(r0,  r1),  cvt_pk_bf16(r2,  r3),
                     cvt_pk_bf16(r4,  r5),  cvt_pk_bf16(r6,  r7) };
        int4v pB = { cvt_pk_bf16(r8,  r9),  cvt_pk_bf16(r10, r11),
                     cvt_pk_bf16(r12, r13), cvt_pk_bf16(r14, r15) };
        short8 wa0 = w2p[(c << 5) + (hi << 3) + e8];
        short8 wa1 = w2p[(c << 5) + 16 + (hi << 3) + e8];
        accA = __builtin_amdgcn_mfma_f32_32x32x16_bf16(
            wa0, __builtin_bit_cast(short8, pA), accA, 0, 0, 0);
        accB = __builtin_amdgcn_mfma_f32_32x32x16_bf16(
            wa1, __builtin_bit_cast(short8, pB), accB, 0, 0, 0);
    }

    // ---- epilogue: +b2, half-split LN2, store ----
    float oi[4];
    #pragma unroll
    for (int i = 0; i < 4; ++i)
        oi[i] = hn[i] + accA[i] + accB[i] + b2[4 * hi + i];
    float ps2 = oi[0] + oi[1] + oi[2] + oi[3];
    float pq2 = oi[0]*oi[0] + oi[1]*oi[1] + oi[2]*oi[2] + oi[3]*oi[3];
    float m2 = (ps2 + __shfl_xor(ps2, 32)) * 0.125f;
    float v2 = (pq2 + __shfl_xor(pq2, 32)) * 0.125f - m2 * m2;
    float rs2 = rsqrtf(v2 + 1e-5f);

    if (valid) {
        f32x4 st;
        #pragma unroll
        for (int i = 0; i < 4; ++i)
            st[i] = (oi[i] - m2) * rs2 * g2[4 * hi + i] + bb2[4 * hi + i];
        *reinterpret_cast<f32x4*>(out + (size_t)T * E + hi * 4) = st;
    }
}

extern "C" void kernel_launch(void* const* d_in, const int* in_sizes, int n_in,
                              void* d_out, int out_size, void* d_ws, size_t ws_size,
                              hipStream_t stream) {
    const float* x       = (const float*)d_in[0];
    const float* Win     = (const float*)d_in[1];
    const float* th_attn = (const float*)d_in[2];
    const float* Wout    = (const float*)d_in[3];
    const float* th_ffn  = (const float*)d_in[4];
    const float* W1      = (const float*)d_in[5];
    const float* b1      = (const float*)d_in[6];
    const float* W2      = (const float*)d_in[7];
    const float* b2      = (const float*)d_in[8];
    const float* g1      = (const float*)d_in[9];
    const float* bb1     = (const float*)d_in[10];
    const float* g2      = (const float*)d_in[11];
    const float* bb2     = (const float*)d_in[12];
    float* out = (float*)d_out;
    (void)d_ws; (void)ws_size;

    const int ntok = in_sizes[0] / E;            // 131072
    const int blocks = (ntok + TPB - 1) / TPB;   // 256
    qtb_kernel<<<blocks, 1024, 0, stream>>>(x, Win, th_attn, Wout, th_ffn,
                                            W1, b1, W2, b2, g1, bb1, g2, bb2,
                                            out, ntok);
}